// Round 1
// baseline (3246.372 us; speedup 1.0000x reference)
//
#include <hip/hip_runtime.h>
#include <hip/hip_bf16.h>
#include <math.h>

#define B_SZ 8192
#define D_SZ 1280
#define NE   4
#define NC   20
#define CD   64
#define NH   4
#define HD   16
#define FF   256

// ---------------- workspace layout (bytes) ----------------
// 0    : cnt[4]   (int)
// 16   : cnt2[4]  (int)
// 32   : off[8]   (int)   (off[0..4] used)
// 64   : topi[2*B] int    (65536)
// 65600: topw[2*B] float  (65536)
// 131136: idx_list[2*B] int (65536)
// 196672: wgt_list[2*B] float (65536)
// 262208: xsf[2*B][D] bf16  (41,943,040)
#define WS_TOPI   64
#define WS_TOPW   (64 + 2*B_SZ*4)
#define WS_IDX    (64 + 4*B_SZ*4)
#define WS_WGT    (64 + 6*B_SZ*4)
#define WS_XSF    (64 + 8*B_SZ*4)

// ================= gate =================
__global__ __launch_bounds__(64) void gate_kernel(
    const float* __restrict__ x, const float* __restrict__ gw1, const float* __restrict__ gb1,
    const float* __restrict__ gw2, const float* __restrict__ gb2,
    int* __restrict__ cnt, int* __restrict__ topi, float* __restrict__ topw,
    float* __restrict__ load_out)
{
    const int b = blockIdx.x;
    const int lane = threadIdx.x;
    float acc[16];
#pragma unroll
    for (int j = 0; j < 16; ++j) acc[j] = 0.f;
    const float* xr = x + (size_t)b * D_SZ;
    for (int t = 0; t < NC; ++t) {
        float xv = xr[t * 64 + lane];
#pragma unroll
        for (int j = 0; j < 16; ++j) acc[j] += xv * gw1[j * D_SZ + t * 64 + lane];
    }
#pragma unroll
    for (int j = 0; j < 16; ++j) {
        acc[j] += __shfl_xor(acc[j], 32, 64);
        acc[j] += __shfl_xor(acc[j], 16, 64);
        acc[j] += __shfl_xor(acc[j], 8, 64);
        acc[j] += __shfl_xor(acc[j], 4, 64);
        acc[j] += __shfl_xor(acc[j], 2, 64);
        acc[j] += __shfl_xor(acc[j], 1, 64);
    }
    if (lane == 0) {
        float h[16];
#pragma unroll
        for (int j = 0; j < 16; ++j) h[j] = tanhf(acc[j] + gb1[j]);
        float l[4];
#pragma unroll
        for (int e = 0; e < 4; ++e) {
            float sv = gb2[e];
#pragma unroll
            for (int j = 0; j < 16; ++j) sv += h[j] * gw2[e * 16 + j];
            l[e] = sv;
        }
        float m = fmaxf(fmaxf(l[0], l[1]), fmaxf(l[2], l[3]));
        float p[4];
        float sum = 0.f;
#pragma unroll
        for (int e = 0; e < 4; ++e) { p[e] = expf(l[e] - m); sum += p[e]; }
#pragma unroll
        for (int e = 0; e < 4; ++e) p[e] /= sum;
        int i1 = 0;
#pragma unroll
        for (int e = 1; e < 4; ++e) if (p[e] > p[i1]) i1 = e;
        int i2 = (i1 == 0) ? 1 : 0;
#pragma unroll
        for (int e = 0; e < 4; ++e) if (e != i1 && p[e] > p[i2]) i2 = e;
        float s1 = p[i1], s2 = p[i2];
        float denom = s1 + s2 + 1e-6f;
        topi[b * 2 + 0] = i1;
        topi[b * 2 + 1] = i2;
        topw[b * 2 + 0] = s1 / denom;
        topw[b * 2 + 1] = s2 / denom;
        atomicAdd(&cnt[i1], 1);
        atomicAdd(&cnt[i2], 1);
        atomicAdd(&load_out[i1], 1.0f);
        atomicAdd(&load_out[i2], 1.0f);
    }
}

__global__ void offset_kernel(const int* __restrict__ cnt, int* __restrict__ offA)
{
    if (threadIdx.x == 0 && blockIdx.x == 0) {
        int a = 0;
#pragma unroll
        for (int e = 0; e < 4; ++e) { offA[e] = a; a += cnt[e]; }
        offA[4] = a;
    }
}

__global__ __launch_bounds__(256) void scatter_kernel(
    const int* __restrict__ topi, const float* __restrict__ topw,
    const int* __restrict__ offA, int* __restrict__ cnt2,
    int* __restrict__ idx_list, float* __restrict__ wgt_list)
{
    int b = blockIdx.x * 256 + threadIdx.x;
    if (b >= B_SZ) return;
#pragma unroll
    for (int k = 0; k < 2; ++k) {
        int e = topi[b * 2 + k];
        int pos = atomicAdd(&cnt2[e], 1);
        int s = offA[e] + pos;
        idx_list[s] = b;
        wgt_list[s] = topw[b * 2 + k];
    }
}

// ================= expert inner (everything except final proj) =================
__device__ __forceinline__ void load_tile(float (*wt)[68], const float* __restrict__ src,
                                          int stride, int t)
{
#pragma unroll
    for (int l = 0; l < 4; ++l) {
        int f4 = t + 256 * l;
        int row = f4 >> 4;
        int kc = (f4 & 15) << 2;
        float4 v = *(const float4*)(src + (size_t)row * stride + kc);
        wt[row][kc + 0] = v.x; wt[row][kc + 1] = v.y;
        wt[row][kc + 2] = v.z; wt[row][kc + 3] = v.w;
    }
}

// dot of wt[lane][0..63] with 5 rows of src (stride floats apart), accumulating into a5
__device__ __forceinline__ void dot64(const float* src, int stride, int wv,
                                      const float (*wt)[68], int lane, float a5[5])
{
    for (int k0 = 0; k0 < 64; k0 += 8) {
        float4 wA = *(const float4*)&wt[lane][k0];
        float4 wB = *(const float4*)&wt[lane][k0 + 4];
#pragma unroll
        for (int ic = 0; ic < 5; ++ic) {
            const float* r = src + (size_t)(wv * 5 + ic) * stride;
            float4 xA = *(const float4*)(r + k0);
            float4 xB = *(const float4*)(r + k0 + 4);
            a5[ic] += wA.x * xA.x + wA.y * xA.y + wA.z * xA.z + wA.w * xA.w
                    + wB.x * xB.x + wB.y * xB.y + wB.z * xB.z + wB.w * xB.w;
        }
    }
}

__global__ __launch_bounds__(256) void expert_inner(
    const float* __restrict__ x, const float* __restrict__ pos,
    const float* __restrict__ n1g, const float* __restrict__ ipw, const float* __restrict__ ipb,
    const float* __restrict__ opw, const float* __restrict__ opb, const float* __restrict__ ls1,
    const float* __restrict__ n2g, const float* __restrict__ fw1, const float* __restrict__ fb1,
    const float* __restrict__ fw2, const float* __restrict__ fb2, const float* __restrict__ ls2,
    const int* __restrict__ offA, const int* __restrict__ idx_list,
    __hip_bfloat16* __restrict__ xsf)
{
    __shared__ float xs[NC][CD];
    __shared__ float xn[NC][CD];     // norm output, reused as attention-out, then norm2 out
    __shared__ float qkv[NC][3 * CD];
    __shared__ float h1s[NC][FF];
    __shared__ float wt[64][68];

    const int t = threadIdx.x;
    const int wv = t >> 6;
    const int lane = t & 63;
    const int s = blockIdx.x;
    const int e = (s >= offA[1]) + (s >= offA[2]) + (s >= offA[3]);
    const int b = idx_list[s];

    // stage 0: load + pos embed
    for (int idx = t; idx < D_SZ; idx += 256)
        xs[idx >> 6][idx & 63] = x[(size_t)b * D_SZ + idx] + pos[e * D_SZ + idx];
    __syncthreads();

    // stage 1: rmsnorm1
    {
        float g = n1g[e * CD + lane];
#pragma unroll
        for (int ic = 0; ic < 5; ++ic) {
            int c = wv * 5 + ic;
            float v = xs[c][lane];
            float ss = v * v;
            ss += __shfl_xor(ss, 32, 64); ss += __shfl_xor(ss, 16, 64);
            ss += __shfl_xor(ss, 8, 64);  ss += __shfl_xor(ss, 4, 64);
            ss += __shfl_xor(ss, 2, 64);  ss += __shfl_xor(ss, 1, 64);
            float n = sqrtf(ss) * 0.125f + 1e-8f;
            xn[c][lane] = v / n * g;
        }
    }
    __syncthreads();

    // stage 2: qkv = xn @ ipw^T + ipb
    for (int p = 0; p < 3; ++p) {
        load_tile(wt, ipw + ((size_t)(e * 192 + p * 64)) * 64, 64, t);
        __syncthreads();
        float bias = ipb[e * 192 + p * 64 + lane];
        float a5[5] = {0, 0, 0, 0, 0};
        dot64(&xn[0][0], CD, wv, wt, lane, a5);
#pragma unroll
        for (int ic = 0; ic < 5; ++ic) qkv[wv * 5 + ic][p * 64 + lane] = a5[ic] + bias;
        __syncthreads();
    }

    // stage 3: attention (lane = h*16+d)
    {
#pragma unroll
        for (int ic = 0; ic < 5; ++ic) {
            int ci = wv * 5 + ic;
            float qv = qkv[ci][lane];
            float sc[NC];
#pragma unroll
            for (int cj = 0; cj < NC; ++cj) {
                float p = qv * qkv[cj][CD + lane];
                p += __shfl_xor(p, 1, 64); p += __shfl_xor(p, 2, 64);
                p += __shfl_xor(p, 4, 64); p += __shfl_xor(p, 8, 64);
                sc[cj] = p * 0.25f;   // HD^-0.5
            }
            float m = sc[0];
#pragma unroll
            for (int cj = 1; cj < NC; ++cj) m = fmaxf(m, sc[cj]);
            float sum = 0.f, o = 0.f;
#pragma unroll
            for (int cj = 0; cj < NC; ++cj) {
                float ee = expf(sc[cj] - m);
                sum += ee;
                o += ee * qkv[cj][2 * CD + lane];
            }
            xn[ci][lane] = o / sum;   // xn now holds attention output
        }
    }
    __syncthreads();

    // stage 4: out_proj + residual (xs += ls1 * (o @ opw^T + opb))
    load_tile(wt, opw + (size_t)e * CD * CD, 64, t);
    __syncthreads();
    {
        float l1 = ls1[e * CD + lane];
        float ob = opb[e * CD + lane];
        float a5[5] = {0, 0, 0, 0, 0};
        dot64(&xn[0][0], CD, wv, wt, lane, a5);
#pragma unroll
        for (int ic = 0; ic < 5; ++ic) {
            int c = wv * 5 + ic;
            xs[c][lane] += l1 * (a5[ic] + ob);
        }
    }
    __syncthreads();

    // stage 5: rmsnorm2
    {
        float g = n2g[e * CD + lane];
#pragma unroll
        for (int ic = 0; ic < 5; ++ic) {
            int c = wv * 5 + ic;
            float v = xs[c][lane];
            float ss = v * v;
            ss += __shfl_xor(ss, 32, 64); ss += __shfl_xor(ss, 16, 64);
            ss += __shfl_xor(ss, 8, 64);  ss += __shfl_xor(ss, 4, 64);
            ss += __shfl_xor(ss, 2, 64);  ss += __shfl_xor(ss, 1, 64);
            float n = sqrtf(ss) * 0.125f + 1e-8f;
            xn[c][lane] = v / n * g;
        }
    }
    __syncthreads();

    // stage 6: ffn1: h1 = relu(xn @ fw1^T + fb1)
    for (int p = 0; p < 4; ++p) {
        load_tile(wt, fw1 + ((size_t)(e * FF + p * 64)) * 64, 64, t);
        __syncthreads();
        float bias = fb1[e * FF + p * 64 + lane];
        float a5[5] = {0, 0, 0, 0, 0};
        dot64(&xn[0][0], CD, wv, wt, lane, a5);
#pragma unroll
        for (int ic = 0; ic < 5; ++ic)
            h1s[wv * 5 + ic][p * 64 + lane] = fmaxf(a5[ic] + bias, 0.f);
        __syncthreads();
    }

    // stage 7: ffn2: y = h1 @ fw2^T + fb2 ; xs += ls2 * y
    {
        float l2 = ls2[e * CD + lane];
        float y5[5];
        float fb = fb2[e * CD + lane];
#pragma unroll
        for (int ic = 0; ic < 5; ++ic) y5[ic] = fb;
        for (int p = 0; p < 4; ++p) {
            load_tile(wt, fw2 + (size_t)(e * CD) * FF + p * 64, FF, t);
            __syncthreads();
            dot64(&h1s[0][0] + p * 64, FF, wv, wt, lane, y5);
            __syncthreads();
        }
#pragma unroll
        for (int ic = 0; ic < 5; ++ic) {
            int c = wv * 5 + ic;
            xs[c][lane] += l2 * y5[ic];
        }
    }
    __syncthreads();

    // stage 8: write xs (bf16) to compacted buffer
    for (int idx = t; idx < D_SZ; idx += 256)
        xsf[(size_t)s * D_SZ + idx] = __float2bfloat16(xs[idx >> 6][idx & 63]);
}

// ================= final proj grouped GEMM (per expert, sequential launches) =================
#define PC_BM 128
#define PC_BN 128
#define PC_BK 16

__global__ __launch_bounds__(256) void expert_proj(
    const __hip_bfloat16* __restrict__ xsf, const float* __restrict__ pw,
    const float* __restrict__ pb, const int* __restrict__ offA,
    const int* __restrict__ idx_list, const float* __restrict__ wgt_list,
    float* __restrict__ out, int e)
{
    __shared__ float As[PC_BK][PC_BM];
    __shared__ float Bs[PC_BK][PC_BN];
    const int base = offA[e];
    const int M = offA[e + 1] - base;
    const int m0 = blockIdx.x * PC_BM;
    if (m0 >= M) return;
    const int n0 = blockIdx.y * PC_BN;
    const int t = threadIdx.x;
    const int tx = t & 15, ty = t >> 4;

    float acc[8][8];
#pragma unroll
    for (int i = 0; i < 8; ++i)
#pragma unroll
        for (int j = 0; j < 8; ++j) acc[i][j] = 0.f;

    const int arow = t >> 1;
    const int akc = (t & 1) * 8;
    const float* pwB = pw + (size_t)e * D_SZ * D_SZ;

    for (int kt = 0; kt < D_SZ; kt += PC_BK) {
        // A tile (bf16 -> f32), guard rows beyond M
        {
            int gm = m0 + arow;
            uint4 raw = make_uint4(0u, 0u, 0u, 0u);
            if (gm < M)
                raw = *(const uint4*)(xsf + (size_t)(base + gm) * D_SZ + kt + akc);
            uint v[4] = {raw.x, raw.y, raw.z, raw.w};
#pragma unroll
            for (int i = 0; i < 4; ++i) {
                As[akc + 2 * i + 0][arow] = __uint_as_float(v[i] << 16);
                As[akc + 2 * i + 1][arow] = __uint_as_float(v[i] & 0xffff0000u);
            }
        }
        // B tile (proj_w rows n, K-major contiguous)
        {
            const float* bsrc = pwB + (size_t)(n0 + arow) * D_SZ + kt + akc;
            float4 b0 = *(const float4*)(bsrc);
            float4 b1 = *(const float4*)(bsrc + 4);
            Bs[akc + 0][arow] = b0.x; Bs[akc + 1][arow] = b0.y;
            Bs[akc + 2][arow] = b0.z; Bs[akc + 3][arow] = b0.w;
            Bs[akc + 4][arow] = b1.x; Bs[akc + 5][arow] = b1.y;
            Bs[akc + 6][arow] = b1.z; Bs[akc + 7][arow] = b1.w;
        }
        __syncthreads();
#pragma unroll
        for (int k = 0; k < PC_BK; ++k) {
            float a[8], bv[8];
            *(float4*)&a[0]  = *(const float4*)&As[k][ty * 8];
            *(float4*)&a[4]  = *(const float4*)&As[k][ty * 8 + 4];
            *(float4*)&bv[0] = *(const float4*)&Bs[k][tx * 8];
            *(float4*)&bv[4] = *(const float4*)&Bs[k][tx * 8 + 4];
#pragma unroll
            for (int i = 0; i < 8; ++i)
#pragma unroll
                for (int j = 0; j < 8; ++j) acc[i][j] += a[i] * bv[j];
        }
        __syncthreads();
    }

    // epilogue: out[row] += w * (acc + pb)   (expert kernels are stream-sequential -> no race)
#pragma unroll
    for (int i = 0; i < 8; ++i) {
        int m = m0 + ty * 8 + i;
        if (m < M) {
            int slot = base + m;
            int brow = idx_list[slot];
            float wgt = wgt_list[slot];
            float* orow = out + (size_t)brow * D_SZ + n0 + tx * 8;
            const float* pbp = pb + (size_t)e * D_SZ + n0 + tx * 8;
            float4 o0 = *(float4*)orow;
            o0.x += wgt * (acc[i][0] + pbp[0]);
            o0.y += wgt * (acc[i][1] + pbp[1]);
            o0.z += wgt * (acc[i][2] + pbp[2]);
            o0.w += wgt * (acc[i][3] + pbp[3]);
            *(float4*)orow = o0;
            float4 o1 = *(float4*)(orow + 4);
            o1.x += wgt * (acc[i][4] + pbp[4]);
            o1.y += wgt * (acc[i][5] + pbp[5]);
            o1.z += wgt * (acc[i][6] + pbp[6]);
            o1.w += wgt * (acc[i][7] + pbp[7]);
            *(float4*)(orow + 4) = o1;
        }
    }
}

// ================= host launcher =================
extern "C" void kernel_launch(void* const* d_in, const int* in_sizes, int n_in,
                              void* d_out, int out_size, void* d_ws, size_t ws_size,
                              hipStream_t stream)
{
    const float* x   = (const float*)d_in[0];
    const float* gw1 = (const float*)d_in[1];
    const float* gb1 = (const float*)d_in[2];
    const float* gw2 = (const float*)d_in[3];
    const float* gb2 = (const float*)d_in[4];
    const float* pos = (const float*)d_in[5];
    const float* n1g = (const float*)d_in[6];
    const float* ipw = (const float*)d_in[7];
    const float* ipb = (const float*)d_in[8];
    const float* opw = (const float*)d_in[9];
    const float* opb = (const float*)d_in[10];
    const float* ls1 = (const float*)d_in[11];
    const float* n2g = (const float*)d_in[12];
    const float* fw1 = (const float*)d_in[13];
    const float* fb1 = (const float*)d_in[14];
    const float* fw2 = (const float*)d_in[15];
    const float* fb2 = (const float*)d_in[16];
    const float* ls2 = (const float*)d_in[17];
    const float* pw  = (const float*)d_in[18];
    const float* pb  = (const float*)d_in[19];

    float* out = (float*)d_out;

    char* ws = (char*)d_ws;
    int*   cnt      = (int*)(ws + 0);
    int*   cnt2     = (int*)(ws + 16);
    int*   offA     = (int*)(ws + 32);
    int*   topi     = (int*)(ws + WS_TOPI);
    float* topw     = (float*)(ws + WS_TOPW);
    int*   idx_list = (int*)(ws + WS_IDX);
    float* wgt_list = (float*)(ws + WS_WGT);
    __hip_bfloat16* xsf = (__hip_bfloat16*)(ws + WS_XSF);

    // zero output (+aux/load slots) and routing counters
    hipMemsetAsync(d_out, 0, (size_t)out_size * sizeof(float), stream);
    hipMemsetAsync(d_ws, 0, 64, stream);

    float* load_out = out + (size_t)B_SZ * D_SZ + 1;  // aux at B*D stays 0

    gate_kernel<<<B_SZ, 64, 0, stream>>>(x, gw1, gb1, gw2, gb2, cnt, topi, topw, load_out);
    offset_kernel<<<1, 64, 0, stream>>>(cnt, offA);
    scatter_kernel<<<B_SZ / 256, 256, 0, stream>>>(topi, topw, offA, cnt2, idx_list, wgt_list);
    expert_inner<<<2 * B_SZ, 256, 0, stream>>>(x, pos, n1g, ipw, ipb, opw, opb, ls1,
                                               n2g, fw1, fb1, fw2, fb2, ls2,
                                               offA, idx_list, xsf);
    for (int e = 0; e < NE; ++e)
        expert_proj<<<dim3(B_SZ / PC_BM, D_SZ / PC_BN), 256, 0, stream>>>(
            xsf, pw, pb, offA, idx_list, wgt_list, out, e);
}

// Round 2
// 1952.718 us; speedup vs baseline: 1.6625x; 1.6625x over previous
//
#include <hip/hip_runtime.h>
#include <hip/hip_bf16.h>
#include <math.h>

#define B_SZ 8192
#define D_SZ 1280
#define NE   4
#define NC   20
#define CD   64
#define NH   4
#define HD   16
#define FF   256

// ---------------- workspace layout (bytes) ----------------
// 0      : cnt[4]   (int)
// 16     : cnt2[4]  (int)
// 32     : off[8]   (int)
// 64     : topi[2*B] int
// +      : topw[2*B] float
// +      : idx_list[2*B] int
// +      : wgt_list[2*B] float
// 262208 : xsf[(2*B+128)][D] bf16   (pad rows so proj GEMM tiles can over-read safely)
// then   : pwb[E][D][D] bf16 (converted proj_w)
#define WS_TOPI   64
#define WS_TOPW   (64 + 2*B_SZ*4)
#define WS_IDX    (64 + 4*B_SZ*4)
#define WS_WGT    (64 + 6*B_SZ*4)
#define WS_XSF    (64 + 8*B_SZ*4)
#define XSF_ROWS  (2*B_SZ + 128)
#define WS_PWB    (WS_XSF + (size_t)XSF_ROWS * D_SZ * 2)

// ================= pw -> bf16 =================
__global__ __launch_bounds__(256) void convert_pw(const float* __restrict__ pw,
                                                  __hip_bfloat16* __restrict__ pwb)
{
    size_t i = ((size_t)blockIdx.x * 256 + threadIdx.x) * 8;   // 6,553,600 / 8 = 819,200 threads
    float4 a = *(const float4*)(pw + i);
    float4 b = *(const float4*)(pw + i + 4);
    __hip_bfloat16 h[8];
    h[0] = __float2bfloat16(a.x); h[1] = __float2bfloat16(a.y);
    h[2] = __float2bfloat16(a.z); h[3] = __float2bfloat16(a.w);
    h[4] = __float2bfloat16(b.x); h[5] = __float2bfloat16(b.y);
    h[6] = __float2bfloat16(b.z); h[7] = __float2bfloat16(b.w);
    *(uint4*)(pwb + i) = *(uint4*)h;
}

// ================= gate =================
__global__ __launch_bounds__(64) void gate_kernel(
    const float* __restrict__ x, const float* __restrict__ gw1, const float* __restrict__ gb1,
    const float* __restrict__ gw2, const float* __restrict__ gb2,
    int* __restrict__ cnt, int* __restrict__ topi, float* __restrict__ topw,
    float* __restrict__ load_out)
{
    const int b = blockIdx.x;
    const int lane = threadIdx.x;
    float acc[16];
#pragma unroll
    for (int j = 0; j < 16; ++j) acc[j] = 0.f;
    const float* xr = x + (size_t)b * D_SZ;
    for (int t = 0; t < NC; ++t) {
        float xv = xr[t * 64 + lane];
#pragma unroll
        for (int j = 0; j < 16; ++j) acc[j] += xv * gw1[j * D_SZ + t * 64 + lane];
    }
#pragma unroll
    for (int j = 0; j < 16; ++j) {
        acc[j] += __shfl_xor(acc[j], 32, 64);
        acc[j] += __shfl_xor(acc[j], 16, 64);
        acc[j] += __shfl_xor(acc[j], 8, 64);
        acc[j] += __shfl_xor(acc[j], 4, 64);
        acc[j] += __shfl_xor(acc[j], 2, 64);
        acc[j] += __shfl_xor(acc[j], 1, 64);
    }
    if (lane == 0) {
        float h[16];
#pragma unroll
        for (int j = 0; j < 16; ++j) h[j] = tanhf(acc[j] + gb1[j]);
        float l[4];
#pragma unroll
        for (int e = 0; e < 4; ++e) {
            float sv = gb2[e];
#pragma unroll
            for (int j = 0; j < 16; ++j) sv += h[j] * gw2[e * 16 + j];
            l[e] = sv;
        }
        float m = fmaxf(fmaxf(l[0], l[1]), fmaxf(l[2], l[3]));
        float p[4];
        float sum = 0.f;
#pragma unroll
        for (int e = 0; e < 4; ++e) { p[e] = expf(l[e] - m); sum += p[e]; }
#pragma unroll
        for (int e = 0; e < 4; ++e) p[e] /= sum;
        int i1 = 0;
#pragma unroll
        for (int e = 1; e < 4; ++e) if (p[e] > p[i1]) i1 = e;
        int i2 = (i1 == 0) ? 1 : 0;
#pragma unroll
        for (int e = 0; e < 4; ++e) if (e != i1 && p[e] > p[i2]) i2 = e;
        float s1 = p[i1], s2 = p[i2];
        float denom = s1 + s2 + 1e-6f;
        topi[b * 2 + 0] = i1;
        topi[b * 2 + 1] = i2;
        topw[b * 2 + 0] = s1 / denom;
        topw[b * 2 + 1] = s2 / denom;
        atomicAdd(&cnt[i1], 1);
        atomicAdd(&cnt[i2], 1);
        atomicAdd(&load_out[i1], 1.0f);
        atomicAdd(&load_out[i2], 1.0f);
    }
}

__global__ void offset_kernel(const int* __restrict__ cnt, int* __restrict__ offA)
{
    if (threadIdx.x == 0 && blockIdx.x == 0) {
        int a = 0;
#pragma unroll
        for (int e = 0; e < 4; ++e) { offA[e] = a; a += cnt[e]; }
        offA[4] = a;
    }
}

__global__ __launch_bounds__(256) void scatter_kernel(
    const int* __restrict__ topi, const float* __restrict__ topw,
    const int* __restrict__ offA, int* __restrict__ cnt2,
    int* __restrict__ idx_list, float* __restrict__ wgt_list)
{
    int b = blockIdx.x * 256 + threadIdx.x;
    if (b >= B_SZ) return;
#pragma unroll
    for (int k = 0; k < 2; ++k) {
        int e = topi[b * 2 + k];
        int pos = atomicAdd(&cnt2[e], 1);
        int s = offA[e] + pos;
        idx_list[s] = b;
        wgt_list[s] = topw[b * 2 + k];
    }
}

// ================= expert inner (everything except final proj) =================
__device__ __forceinline__ void load_tile(float (*wt)[68], const float* __restrict__ src,
                                          int stride, int t)
{
#pragma unroll
    for (int l = 0; l < 4; ++l) {
        int f4 = t + 256 * l;
        int row = f4 >> 4;
        int kc = (f4 & 15) << 2;
        float4 v = *(const float4*)(src + (size_t)row * stride + kc);
        wt[row][kc + 0] = v.x; wt[row][kc + 1] = v.y;
        wt[row][kc + 2] = v.z; wt[row][kc + 3] = v.w;
    }
}

__device__ __forceinline__ void dot64(const float* src, int stride, int wv,
                                      const float (*wt)[68], int lane, float a5[5])
{
    for (int k0 = 0; k0 < 64; k0 += 8) {
        float4 wA = *(const float4*)&wt[lane][k0];
        float4 wB = *(const float4*)&wt[lane][k0 + 4];
#pragma unroll
        for (int ic = 0; ic < 5; ++ic) {
            const float* r = src + (size_t)(wv * 5 + ic) * stride;
            float4 xA = *(const float4*)(r + k0);
            float4 xB = *(const float4*)(r + k0 + 4);
            a5[ic] += wA.x * xA.x + wA.y * xA.y + wA.z * xA.z + wA.w * xA.w
                    + wB.x * xB.x + wB.y * xB.y + wB.z * xB.z + wB.w * xB.w;
        }
    }
}

__global__ __launch_bounds__(256) void expert_inner(
    const float* __restrict__ x, const float* __restrict__ pos,
    const float* __restrict__ n1g, const float* __restrict__ ipw, const float* __restrict__ ipb,
    const float* __restrict__ opw, const float* __restrict__ opb, const float* __restrict__ ls1,
    const float* __restrict__ n2g, const float* __restrict__ fw1, const float* __restrict__ fb1,
    const float* __restrict__ fw2, const float* __restrict__ fb2, const float* __restrict__ ls2,
    const int* __restrict__ offA, const int* __restrict__ idx_list,
    __hip_bfloat16* __restrict__ xsf)
{
    __shared__ float xs[NC][CD];        // 5 KB
    __shared__ float xn[NC][CD];        // 5 KB
    __shared__ float un[NC][FF];        // 20 KB — qkv ([NC][192]) until stage 3, then h1s
    __shared__ float wt[64][68];        // 17 KB   => total 47 KB -> 3 blocks/CU

    float* qkvf = &un[0][0];            // stride 192 view (dead after stage 3)

    const int t = threadIdx.x;
    const int wv = t >> 6;
    const int lane = t & 63;
    const int s = blockIdx.x;
    const int e = (s >= offA[1]) + (s >= offA[2]) + (s >= offA[3]);
    const int b = idx_list[s];

    // stage 0: load + pos embed
    for (int idx = t; idx < D_SZ; idx += 256)
        xs[idx >> 6][idx & 63] = x[(size_t)b * D_SZ + idx] + pos[e * D_SZ + idx];
    __syncthreads();

    // stage 1: rmsnorm1
    {
        float g = n1g[e * CD + lane];
#pragma unroll
        for (int ic = 0; ic < 5; ++ic) {
            int c = wv * 5 + ic;
            float v = xs[c][lane];
            float ss = v * v;
            ss += __shfl_xor(ss, 32, 64); ss += __shfl_xor(ss, 16, 64);
            ss += __shfl_xor(ss, 8, 64);  ss += __shfl_xor(ss, 4, 64);
            ss += __shfl_xor(ss, 2, 64);  ss += __shfl_xor(ss, 1, 64);
            float n = sqrtf(ss) * 0.125f + 1e-8f;
            xn[c][lane] = v / n * g;
        }
    }
    __syncthreads();

    // stage 2: qkv = xn @ ipw^T + ipb
    for (int p = 0; p < 3; ++p) {
        load_tile(wt, ipw + ((size_t)(e * 192 + p * 64)) * 64, 64, t);
        __syncthreads();
        float bias = ipb[e * 192 + p * 64 + lane];
        float a5[5] = {0, 0, 0, 0, 0};
        dot64(&xn[0][0], CD, wv, wt, lane, a5);
#pragma unroll
        for (int ic = 0; ic < 5; ++ic) qkvf[(wv * 5 + ic) * 192 + p * 64 + lane] = a5[ic] + bias;
        __syncthreads();
    }

    // stage 3: attention (lane = h*16+d)
    {
#pragma unroll
        for (int ic = 0; ic < 5; ++ic) {
            int ci = wv * 5 + ic;
            float qv = qkvf[ci * 192 + lane];
            float sc[NC];
#pragma unroll
            for (int cj = 0; cj < NC; ++cj) {
                float p = qv * qkvf[cj * 192 + 64 + lane];
                p += __shfl_xor(p, 1, 64); p += __shfl_xor(p, 2, 64);
                p += __shfl_xor(p, 4, 64); p += __shfl_xor(p, 8, 64);
                sc[cj] = p * 0.25f;   // HD^-0.5
            }
            float m = sc[0];
#pragma unroll
            for (int cj = 1; cj < NC; ++cj) m = fmaxf(m, sc[cj]);
            float sum = 0.f, o = 0.f;
#pragma unroll
            for (int cj = 0; cj < NC; ++cj) {
                float ee = __expf(sc[cj] - m);
                sum += ee;
                o += ee * qkvf[cj * 192 + 128 + lane];
            }
            xn[ci][lane] = o / sum;   // xn now holds attention output
        }
    }
    __syncthreads();

    // stage 4: out_proj + residual (xs += ls1 * (o @ opw^T + opb))
    load_tile(wt, opw + (size_t)e * CD * CD, 64, t);
    __syncthreads();
    {
        float l1 = ls1[e * CD + lane];
        float ob = opb[e * CD + lane];
        float a5[5] = {0, 0, 0, 0, 0};
        dot64(&xn[0][0], CD, wv, wt, lane, a5);
#pragma unroll
        for (int ic = 0; ic < 5; ++ic) {
            int c = wv * 5 + ic;
            xs[c][lane] += l1 * (a5[ic] + ob);
        }
    }
    __syncthreads();

    // stage 5: rmsnorm2
    {
        float g = n2g[e * CD + lane];
#pragma unroll
        for (int ic = 0; ic < 5; ++ic) {
            int c = wv * 5 + ic;
            float v = xs[c][lane];
            float ss = v * v;
            ss += __shfl_xor(ss, 32, 64); ss += __shfl_xor(ss, 16, 64);
            ss += __shfl_xor(ss, 8, 64);  ss += __shfl_xor(ss, 4, 64);
            ss += __shfl_xor(ss, 2, 64);  ss += __shfl_xor(ss, 1, 64);
            float n = sqrtf(ss) * 0.125f + 1e-8f;
            xn[c][lane] = v / n * g;
        }
    }
    __syncthreads();

    // stage 6: ffn1: h1 = relu(xn @ fw1^T + fb1)   (h1s overlays qkv region)
    for (int p = 0; p < 4; ++p) {
        load_tile(wt, fw1 + ((size_t)(e * FF + p * 64)) * 64, 64, t);
        __syncthreads();
        float bias = fb1[e * FF + p * 64 + lane];
        float a5[5] = {0, 0, 0, 0, 0};
        dot64(&xn[0][0], CD, wv, wt, lane, a5);
#pragma unroll
        for (int ic = 0; ic < 5; ++ic)
            un[wv * 5 + ic][p * 64 + lane] = fmaxf(a5[ic] + bias, 0.f);
        __syncthreads();
    }

    // stage 7: ffn2: y = h1 @ fw2^T + fb2 ; xs += ls2 * y
    {
        float l2 = ls2[e * CD + lane];
        float y5[5];
        float fb = fb2[e * CD + lane];
#pragma unroll
        for (int ic = 0; ic < 5; ++ic) y5[ic] = fb;
        for (int p = 0; p < 4; ++p) {
            load_tile(wt, fw2 + (size_t)(e * CD) * FF + p * 64, FF, t);
            __syncthreads();
            dot64(&un[0][0] + p * 64, FF, wv, wt, lane, y5);
            __syncthreads();
        }
#pragma unroll
        for (int ic = 0; ic < 5; ++ic) {
            int c = wv * 5 + ic;
            xs[c][lane] += l2 * y5[ic];
        }
    }
    __syncthreads();

    // stage 8: write xs (bf16) to compacted buffer
    for (int idx = t; idx < D_SZ; idx += 256)
        xsf[(size_t)s * D_SZ + idx] = __float2bfloat16(xs[idx >> 6][idx & 63]);
}

// ================= final proj grouped GEMM — bf16 MFMA =================
// Tile 128x128, BK=64. LDS layout [kb][row][8 bf16] (kb = k-octet), row-dim padded
// 128->130 so staging writes and fragment reads are <=2-way bank aliasing (free).
// MFMA fragment facts (learn_hip m89/m91): A/B operand row|col = lane&15,
// k = (lane>>4)*8+j ; C/D col = lane&15, row = (lane>>4)*4 + reg.
#define PROWP 130

__global__ __launch_bounds__(256) void expert_proj_mfma(
    const __hip_bfloat16* __restrict__ xsf, const __hip_bfloat16* __restrict__ pwb,
    const float* __restrict__ pb, const int* __restrict__ offA,
    const int* __restrict__ idx_list, const float* __restrict__ wgt_list,
    float* __restrict__ out, int e)
{
    typedef __attribute__((ext_vector_type(8))) short bf16x8;
    typedef __attribute__((ext_vector_type(4))) float f32x4;

    __shared__ short As[8][PROWP][8];   // 16.25 KB
    __shared__ short Bs[8][PROWP][8];

    const int base = offA[e];
    const int M = offA[e + 1] - base;
    const int m0 = blockIdx.x * 128;
    if (m0 >= M) return;
    const int n0 = blockIdx.y * 128;
    const int t = threadIdx.x;
    const int w = t >> 6, lane = t & 63;
    const int wm = (w & 1) * 64, wn = (w >> 1) * 64;
    const int l15 = lane & 15, lg = lane >> 4;

    f32x4 acc[4][4];
#pragma unroll
    for (int i = 0; i < 4; ++i)
#pragma unroll
        for (int j = 0; j < 4; ++j) acc[i][j] = (f32x4){0.f, 0.f, 0.f, 0.f};

    const __hip_bfloat16* Ag = xsf + (size_t)(base + m0) * D_SZ;   // over-reads land in padded rows
    const __hip_bfloat16* Bg = pwb + (size_t)e * D_SZ * D_SZ + (size_t)n0 * D_SZ;

    for (int kt = 0; kt < D_SZ; kt += 64) {
        __syncthreads();
#pragma unroll
        for (int i = 0; i < 4; ++i) {
            int chunk = i * 256 + t;          // 0..1023
            int row = chunk >> 3, kb = chunk & 7;
            *(uint4*)&As[kb][row][0] = *(const uint4*)(Ag + (size_t)row * D_SZ + kt + kb * 8);
            *(uint4*)&Bs[kb][row][0] = *(const uint4*)(Bg + (size_t)row * D_SZ + kt + kb * 8);
        }
        __syncthreads();
#pragma unroll
        for (int ks = 0; ks < 2; ++ks) {
            int kb = ks * 4 + lg;
            bf16x8 af[4], bfr[4];
#pragma unroll
            for (int ti = 0; ti < 4; ++ti) af[ti]  = *(const bf16x8*)&As[kb][wm + ti * 16 + l15][0];
#pragma unroll
            for (int tj = 0; tj < 4; ++tj) bfr[tj] = *(const bf16x8*)&Bs[kb][wn + tj * 16 + l15][0];
#pragma unroll
            for (int ti = 0; ti < 4; ++ti)
#pragma unroll
                for (int tj = 0; tj < 4; ++tj)
                    acc[ti][tj] = __builtin_amdgcn_mfma_f32_16x16x32_bf16(
                        af[ti], bfr[tj], acc[ti][tj], 0, 0, 0);
        }
    }

    // epilogue: out[brow] += w * (acc + pb)   (per-expert sequential launches -> race-free)
    float pbv[4];
#pragma unroll
    for (int tj = 0; tj < 4; ++tj) pbv[tj] = pb[(size_t)e * D_SZ + n0 + wn + tj * 16 + l15];

#pragma unroll
    for (int ti = 0; ti < 4; ++ti) {
#pragma unroll
        for (int r = 0; r < 4; ++r) {
            int m = m0 + wm + ti * 16 + lg * 4 + r;
            if (m < M) {
                int slot = base + m;
                int brow = idx_list[slot];
                float wv = wgt_list[slot];
                float* orow = out + (size_t)brow * D_SZ + n0 + wn + l15;
#pragma unroll
                for (int tj = 0; tj < 4; ++tj)
                    orow[tj * 16] += wv * (acc[ti][tj][r] + pbv[tj]);
            }
        }
    }
}

// ================= host launcher =================
extern "C" void kernel_launch(void* const* d_in, const int* in_sizes, int n_in,
                              void* d_out, int out_size, void* d_ws, size_t ws_size,
                              hipStream_t stream)
{
    const float* x   = (const float*)d_in[0];
    const float* gw1 = (const float*)d_in[1];
    const float* gb1 = (const float*)d_in[2];
    const float* gw2 = (const float*)d_in[3];
    const float* gb2 = (const float*)d_in[4];
    const float* pos = (const float*)d_in[5];
    const float* n1g = (const float*)d_in[6];
    const float* ipw = (const float*)d_in[7];
    const float* ipb = (const float*)d_in[8];
    const float* opw = (const float*)d_in[9];
    const float* opb = (const float*)d_in[10];
    const float* ls1 = (const float*)d_in[11];
    const float* n2g = (const float*)d_in[12];
    const float* fw1 = (const float*)d_in[13];
    const float* fb1 = (const float*)d_in[14];
    const float* fw2 = (const float*)d_in[15];
    const float* fb2 = (const float*)d_in[16];
    const float* ls2 = (const float*)d_in[17];
    const float* pw  = (const float*)d_in[18];
    const float* pb  = (const float*)d_in[19];

    float* out = (float*)d_out;

    char* ws = (char*)d_ws;
    int*   cnt      = (int*)(ws + 0);
    int*   cnt2     = (int*)(ws + 16);
    int*   offA     = (int*)(ws + 32);
    int*   topi     = (int*)(ws + WS_TOPI);
    float* topw     = (float*)(ws + WS_TOPW);
    int*   idx_list = (int*)(ws + WS_IDX);
    float* wgt_list = (float*)(ws + WS_WGT);
    __hip_bfloat16* xsf = (__hip_bfloat16*)(ws + WS_XSF);
    __hip_bfloat16* pwb = (__hip_bfloat16*)(ws + WS_PWB);

    hipMemsetAsync(d_out, 0, (size_t)out_size * sizeof(float), stream);
    hipMemsetAsync(d_ws, 0, 64, stream);

    float* load_out = out + (size_t)B_SZ * D_SZ + 1;  // aux at B*D stays 0

    convert_pw<<<NE * D_SZ * D_SZ / (256 * 8), 256, 0, stream>>>(pw, pwb);
    gate_kernel<<<B_SZ, 64, 0, stream>>>(x, gw1, gb1, gw2, gb2, cnt, topi, topw, load_out);
    offset_kernel<<<1, 64, 0, stream>>>(cnt, offA);
    scatter_kernel<<<B_SZ / 256, 256, 0, stream>>>(topi, topw, offA, cnt2, idx_list, wgt_list);
    expert_inner<<<2 * B_SZ, 256, 0, stream>>>(x, pos, n1g, ipw, ipb, opw, opb, ls1,
                                               n2g, fw1, fb1, fw2, fb2, ls2,
                                               offA, idx_list, xsf);
    for (int e = 0; e < NE; ++e)
        expert_proj_mfma<<<dim3(B_SZ / 128, D_SZ / 128), 256, 0, stream>>>(
            xsf, pwb, pb, offA, idx_list, wgt_list, out, e);
}

// Round 3
// 1119.183 us; speedup vs baseline: 2.9007x; 1.7448x over previous
//
#include <hip/hip_runtime.h>
#include <hip/hip_bf16.h>
#include <math.h>

#define B_SZ 8192
#define D_SZ 1280
#define NE   4
#define NC   20
#define CD   64
#define NH   4
#define HD   16
#define FF   256

typedef __attribute__((ext_vector_type(8))) short bf16x8;
typedef __attribute__((ext_vector_type(4))) float f32x4;

// ---------------- workspace layout (bytes) ----------------
#define WS_TOPI   64
#define WS_TOPW   (64 + 2*B_SZ*4)
#define WS_IDX    (64 + 4*B_SZ*4)
#define WS_WGT    (64 + 6*B_SZ*4)
#define WS_XSF    (64 + 8*B_SZ*4)
#define XSF_ROWS  (2*B_SZ + 128)
#define WS_PWB    (WS_XSF + (size_t)XSF_ROWS * D_SZ * 2)
#define WS_IPWB   (WS_PWB  + (size_t)NE * D_SZ * D_SZ * 2)
#define WS_OPWB   (WS_IPWB + (size_t)NE * 192 * 64 * 2)
#define WS_FW1B   (WS_OPWB + (size_t)NE * 64 * 64 * 2)
#define WS_FW2B   (WS_FW1B + (size_t)NE * 256 * 64 * 2)
// end: WS_FW2B + 4*64*256*2  (~56 MB total)

// ================= weight conversion =================
__global__ __launch_bounds__(256) void convert_pw(const float* __restrict__ pw,
                                                  __hip_bfloat16* __restrict__ pwb)
{
    size_t i = ((size_t)blockIdx.x * 256 + threadIdx.x) * 8;
    float4 a = *(const float4*)(pw + i);
    float4 b = *(const float4*)(pw + i + 4);
    __hip_bfloat16 h[8];
    h[0] = __float2bfloat16(a.x); h[1] = __float2bfloat16(a.y);
    h[2] = __float2bfloat16(a.z); h[3] = __float2bfloat16(a.w);
    h[4] = __float2bfloat16(b.x); h[5] = __float2bfloat16(b.y);
    h[6] = __float2bfloat16(b.z); h[7] = __float2bfloat16(b.w);
    *(uint4*)(pwb + i) = *(uint4*)h;
}

// converts ipw/opw/fw1/fw2 in one launch (regions are multiples of 8 elements)
#define N_IPW (NE*192*64)
#define N_OPW (NE*64*64)
#define N_FW1 (NE*256*64)
#define N_FW2 (NE*64*256)
__global__ __launch_bounds__(256) void convert_small(
    const float* __restrict__ ipw, const float* __restrict__ opw,
    const float* __restrict__ fw1, const float* __restrict__ fw2,
    __hip_bfloat16* __restrict__ ipwb, __hip_bfloat16* __restrict__ opwb,
    __hip_bfloat16* __restrict__ fw1b, __hip_bfloat16* __restrict__ fw2b)
{
    size_t i = ((size_t)blockIdx.x * 256 + threadIdx.x) * 8;
    const float* src; __hip_bfloat16* dst; size_t off;
    if (i < N_IPW)                       { src = ipw; dst = ipwb; off = i; }
    else if (i < N_IPW + N_OPW)          { src = opw; dst = opwb; off = i - N_IPW; }
    else if (i < N_IPW + N_OPW + N_FW1)  { src = fw1; dst = fw1b; off = i - N_IPW - N_OPW; }
    else                                 { src = fw2; dst = fw2b; off = i - N_IPW - N_OPW - N_FW1; }
    float4 a = *(const float4*)(src + off);
    float4 b = *(const float4*)(src + off + 4);
    __hip_bfloat16 h[8];
    h[0] = __float2bfloat16(a.x); h[1] = __float2bfloat16(a.y);
    h[2] = __float2bfloat16(a.z); h[3] = __float2bfloat16(a.w);
    h[4] = __float2bfloat16(b.x); h[5] = __float2bfloat16(b.y);
    h[6] = __float2bfloat16(b.z); h[7] = __float2bfloat16(b.w);
    *(uint4*)(dst + off) = *(uint4*)h;
}

// ================= gate =================
__global__ __launch_bounds__(64) void gate_kernel(
    const float* __restrict__ x, const float* __restrict__ gw1, const float* __restrict__ gb1,
    const float* __restrict__ gw2, const float* __restrict__ gb2,
    int* __restrict__ cnt, int* __restrict__ topi, float* __restrict__ topw,
    float* __restrict__ load_out)
{
    const int b = blockIdx.x;
    const int lane = threadIdx.x;
    float acc[16];
#pragma unroll
    for (int j = 0; j < 16; ++j) acc[j] = 0.f;
    const float* xr = x + (size_t)b * D_SZ;
    for (int t = 0; t < NC; ++t) {
        float xv = xr[t * 64 + lane];
#pragma unroll
        for (int j = 0; j < 16; ++j) acc[j] += xv * gw1[j * D_SZ + t * 64 + lane];
    }
#pragma unroll
    for (int j = 0; j < 16; ++j) {
        acc[j] += __shfl_xor(acc[j], 32, 64);
        acc[j] += __shfl_xor(acc[j], 16, 64);
        acc[j] += __shfl_xor(acc[j], 8, 64);
        acc[j] += __shfl_xor(acc[j], 4, 64);
        acc[j] += __shfl_xor(acc[j], 2, 64);
        acc[j] += __shfl_xor(acc[j], 1, 64);
    }
    if (lane == 0) {
        float h[16];
#pragma unroll
        for (int j = 0; j < 16; ++j) h[j] = tanhf(acc[j] + gb1[j]);
        float l[4];
#pragma unroll
        for (int e = 0; e < 4; ++e) {
            float sv = gb2[e];
#pragma unroll
            for (int j = 0; j < 16; ++j) sv += h[j] * gw2[e * 16 + j];
            l[e] = sv;
        }
        float m = fmaxf(fmaxf(l[0], l[1]), fmaxf(l[2], l[3]));
        float p[4];
        float sum = 0.f;
#pragma unroll
        for (int e = 0; e < 4; ++e) { p[e] = expf(l[e] - m); sum += p[e]; }
#pragma unroll
        for (int e = 0; e < 4; ++e) p[e] /= sum;
        int i1 = 0;
#pragma unroll
        for (int e = 1; e < 4; ++e) if (p[e] > p[i1]) i1 = e;
        int i2 = (i1 == 0) ? 1 : 0;
#pragma unroll
        for (int e = 0; e < 4; ++e) if (e != i1 && p[e] > p[i2]) i2 = e;
        float s1 = p[i1], s2 = p[i2];
        float denom = s1 + s2 + 1e-6f;
        topi[b * 2 + 0] = i1;
        topi[b * 2 + 1] = i2;
        topw[b * 2 + 0] = s1 / denom;
        topw[b * 2 + 1] = s2 / denom;
        atomicAdd(&cnt[i1], 1);
        atomicAdd(&cnt[i2], 1);
        atomicAdd(&load_out[i1], 1.0f);
        atomicAdd(&load_out[i2], 1.0f);
    }
}

__global__ void offset_kernel(const int* __restrict__ cnt, int* __restrict__ offA)
{
    if (threadIdx.x == 0 && blockIdx.x == 0) {
        int a = 0;
#pragma unroll
        for (int e = 0; e < 4; ++e) { offA[e] = a; a += cnt[e]; }
        offA[4] = a;
    }
}

__global__ __launch_bounds__(256) void scatter_kernel(
    const int* __restrict__ topi, const float* __restrict__ topw,
    const int* __restrict__ offA, int* __restrict__ cnt2,
    int* __restrict__ idx_list, float* __restrict__ wgt_list)
{
    int b = blockIdx.x * 256 + threadIdx.x;
    if (b >= B_SZ) return;
#pragma unroll
    for (int k = 0; k < 2; ++k) {
        int e = topi[b * 2 + k];
        int pos = atomicAdd(&cnt2[e], 1);
        int s = offA[e] + pos;
        idx_list[s] = b;
        wgt_list[s] = topw[b * 2 + k];
    }
}

// ================= expert inner — MFMA =================
// One slot per block, 4 waves. M=20 rows padded to 32 for 16x16x32 MFMA.
// Garbage in pad rows (20..31) is row-confined in C and discarded on writeback.
// LDS activation buffers bf16 with row stride mult-of-8 (16B-aligned frags),
// stride/2 ≡ 4 mod 32 → 2-way bank aliasing max (free, m136).
__global__ __launch_bounds__(256) void expert_inner(
    const float* __restrict__ x, const float* __restrict__ pos,
    const float* __restrict__ n1g,
    const __hip_bfloat16* __restrict__ ipwb, const float* __restrict__ ipb,
    const __hip_bfloat16* __restrict__ opwb, const float* __restrict__ opb,
    const float* __restrict__ ls1, const float* __restrict__ n2g,
    const __hip_bfloat16* __restrict__ fw1b, const float* __restrict__ fb1,
    const __hip_bfloat16* __restrict__ fw2b, const float* __restrict__ fb2,
    const float* __restrict__ ls2,
    const int* __restrict__ offA, const int* __restrict__ idx_list,
    __hip_bfloat16* __restrict__ xsf)
{
    __shared__ float xs[NC][66];               // 5.28 KB residual (fp32)
    __shared__ __hip_bfloat16 xnb[32][72];     // 4.6 KB  A operand (norm1/attn-out/norm2)
    __shared__ __hip_bfloat16 qkvb[32][200];   // 12.8 KB qkv
    __shared__ __hip_bfloat16 h1b[32][264];    // 16.9 KB ffn hidden

    const int t = threadIdx.x;
    const int w = t >> 6;
    const int lane = t & 63;
    const int l15 = lane & 15, lg = lane >> 4;
    const int s = blockIdx.x;
    const int e = (s >= offA[1]) + (s >= offA[2]) + (s >= offA[3]);
    const int b = idx_list[s];

    // stage 0: load + pos embed
    for (int idx = t; idx < D_SZ; idx += 256)
        xs[idx >> 6][idx & 63] = x[(size_t)b * D_SZ + idx] + pos[e * D_SZ + idx];
    __syncthreads();

    // stage 1: rmsnorm1 -> xnb (bf16)
    {
        float g = n1g[e * CD + lane];
#pragma unroll
        for (int ic = 0; ic < 5; ++ic) {
            int c = w * 5 + ic;
            float v = xs[c][lane];
            float ss = v * v;
            ss += __shfl_xor(ss, 32, 64); ss += __shfl_xor(ss, 16, 64);
            ss += __shfl_xor(ss, 8, 64);  ss += __shfl_xor(ss, 4, 64);
            ss += __shfl_xor(ss, 2, 64);  ss += __shfl_xor(ss, 1, 64);
            float n = sqrtf(ss) * 0.125f + 1e-8f;
            xnb[c][lane] = __float2bfloat16(v / n * g);
        }
    }
    __syncthreads();

    // stage 2: qkv = xn @ ipw^T + ipb   (MFMA, 12 n-tiles / 4 waves)
    {
        bf16x8 af[2][2];
#pragma unroll
        for (int mt = 0; mt < 2; ++mt)
#pragma unroll
            for (int ks = 0; ks < 2; ++ks)
                af[mt][ks] = *(const bf16x8*)&xnb[mt * 16 + l15][ks * 32 + lg * 8];
#pragma unroll
        for (int i = 0; i < 3; ++i) {
            int n = (w * 3 + i) * 16 + l15;
            f32x4 acc[2] = {{0,0,0,0},{0,0,0,0}};
#pragma unroll
            for (int ks = 0; ks < 2; ++ks) {
                bf16x8 bf = *(const bf16x8*)(ipwb + ((size_t)(e * 192 + n)) * 64 + ks * 32 + lg * 8);
#pragma unroll
                for (int mt = 0; mt < 2; ++mt)
                    acc[mt] = __builtin_amdgcn_mfma_f32_16x16x32_bf16(af[mt][ks], bf, acc[mt], 0, 0, 0);
            }
            float bias = ipb[e * 192 + n];
#pragma unroll
            for (int mt = 0; mt < 2; ++mt)
#pragma unroll
                for (int r = 0; r < 4; ++r)
                    qkvb[mt * 16 + lg * 4 + r][n] = __float2bfloat16(acc[mt][r] + bias);
        }
    }
    __syncthreads();

    // stage 3: attention (lane = h*16+d), write attn-out into xnb
    {
#pragma unroll
        for (int ic = 0; ic < 5; ++ic) {
            int ci = w * 5 + ic;
            float qv = __bfloat162float(qkvb[ci][lane]);
            float sc[NC];
#pragma unroll
            for (int cj = 0; cj < NC; ++cj) {
                float p = qv * __bfloat162float(qkvb[cj][64 + lane]);
                p += __shfl_xor(p, 1, 64); p += __shfl_xor(p, 2, 64);
                p += __shfl_xor(p, 4, 64); p += __shfl_xor(p, 8, 64);
                sc[cj] = p * 0.25f;   // HD^-0.5
            }
            float m = sc[0];
#pragma unroll
            for (int cj = 1; cj < NC; ++cj) m = fmaxf(m, sc[cj]);
            float sum = 0.f, o = 0.f;
#pragma unroll
            for (int cj = 0; cj < NC; ++cj) {
                float ee = __expf(sc[cj] - m);
                sum += ee;
                o += ee * __bfloat162float(qkvb[cj][128 + lane]);
            }
            xnb[ci][lane] = __float2bfloat16(o / sum);
        }
    }
    __syncthreads();

    // stage 4: out_proj (MFMA) + residual: xs += ls1*(o @ opw^T + opb)
    {
        bf16x8 af[2][2];
#pragma unroll
        for (int mt = 0; mt < 2; ++mt)
#pragma unroll
            for (int ks = 0; ks < 2; ++ks)
                af[mt][ks] = *(const bf16x8*)&xnb[mt * 16 + l15][ks * 32 + lg * 8];
        int n = w * 16 + l15;
        f32x4 acc[2] = {{0,0,0,0},{0,0,0,0}};
#pragma unroll
        for (int ks = 0; ks < 2; ++ks) {
            bf16x8 bf = *(const bf16x8*)(opwb + ((size_t)(e * 64 + n)) * 64 + ks * 32 + lg * 8);
#pragma unroll
            for (int mt = 0; mt < 2; ++mt)
                acc[mt] = __builtin_amdgcn_mfma_f32_16x16x32_bf16(af[mt][ks], bf, acc[mt], 0, 0, 0);
        }
        float l1v = ls1[e * 64 + n], ob = opb[e * 64 + n];
#pragma unroll
        for (int mt = 0; mt < 2; ++mt)
#pragma unroll
            for (int r = 0; r < 4; ++r) {
                int m = mt * 16 + lg * 4 + r;
                if (m < NC) xs[m][n] += l1v * (acc[mt][r] + ob);
            }
    }
    __syncthreads();

    // stage 5: rmsnorm2 -> xnb
    {
        float g = n2g[e * CD + lane];
#pragma unroll
        for (int ic = 0; ic < 5; ++ic) {
            int c = w * 5 + ic;
            float v = xs[c][lane];
            float ss = v * v;
            ss += __shfl_xor(ss, 32, 64); ss += __shfl_xor(ss, 16, 64);
            ss += __shfl_xor(ss, 8, 64);  ss += __shfl_xor(ss, 4, 64);
            ss += __shfl_xor(ss, 2, 64);  ss += __shfl_xor(ss, 1, 64);
            float n = sqrtf(ss) * 0.125f + 1e-8f;
            xnb[c][lane] = __float2bfloat16(v / n * g);
        }
    }
    __syncthreads();

    // stage 6: ffn1 (MFMA): h1 = relu(xn2 @ fw1^T + fb1), 16 n-tiles / 4 waves
    {
        bf16x8 af[2][2];
#pragma unroll
        for (int mt = 0; mt < 2; ++mt)
#pragma unroll
            for (int ks = 0; ks < 2; ++ks)
                af[mt][ks] = *(const bf16x8*)&xnb[mt * 16 + l15][ks * 32 + lg * 8];
#pragma unroll
        for (int i = 0; i < 4; ++i) {
            int n = (w * 4 + i) * 16 + l15;
            f32x4 acc[2] = {{0,0,0,0},{0,0,0,0}};
#pragma unroll
            for (int ks = 0; ks < 2; ++ks) {
                bf16x8 bf = *(const bf16x8*)(fw1b + ((size_t)(e * 256 + n)) * 64 + ks * 32 + lg * 8);
#pragma unroll
                for (int mt = 0; mt < 2; ++mt)
                    acc[mt] = __builtin_amdgcn_mfma_f32_16x16x32_bf16(af[mt][ks], bf, acc[mt], 0, 0, 0);
            }
            float b1 = fb1[e * 256 + n];
#pragma unroll
            for (int mt = 0; mt < 2; ++mt)
#pragma unroll
                for (int r = 0; r < 4; ++r)
                    h1b[mt * 16 + lg * 4 + r][n] = __float2bfloat16(fmaxf(acc[mt][r] + b1, 0.f));
        }
    }
    __syncthreads();

    // stage 7: ffn2 (MFMA, K=256): xs += ls2*(h1 @ fw2^T + fb2)
    {
        int n = w * 16 + l15;
        f32x4 acc[2] = {{0,0,0,0},{0,0,0,0}};
#pragma unroll
        for (int ks = 0; ks < 8; ++ks) {
            bf16x8 bf = *(const bf16x8*)(fw2b + ((size_t)(e * 64 + n)) * 256 + ks * 32 + lg * 8);
#pragma unroll
            for (int mt = 0; mt < 2; ++mt) {
                bf16x8 af = *(const bf16x8*)&h1b[mt * 16 + l15][ks * 32 + lg * 8];
                acc[mt] = __builtin_amdgcn_mfma_f32_16x16x32_bf16(af, bf, acc[mt], 0, 0, 0);
            }
        }
        float l2v = ls2[e * 64 + n], b2 = fb2[e * 64 + n];
#pragma unroll
        for (int mt = 0; mt < 2; ++mt)
#pragma unroll
            for (int r = 0; r < 4; ++r) {
                int m = mt * 16 + lg * 4 + r;
                if (m < NC) xs[m][n] += l2v * (acc[mt][r] + b2);
            }
    }
    __syncthreads();

    // stage 8: write xs (bf16)
    for (int idx = t; idx < D_SZ; idx += 256)
        xsf[(size_t)s * D_SZ + idx] = __float2bfloat16(xs[idx >> 6][idx & 63]);
}

// ================= final proj grouped GEMM — bf16 MFMA, all experts in one launch =================
#define PROWP 130

__global__ __launch_bounds__(256) void expert_proj_mfma(
    const __hip_bfloat16* __restrict__ xsf, const __hip_bfloat16* __restrict__ pwb,
    const float* __restrict__ pb, const int* __restrict__ offA,
    const int* __restrict__ idx_list, const float* __restrict__ wgt_list,
    float* __restrict__ out)
{
    __shared__ short As[8][PROWP][8];
    __shared__ short Bs[8][PROWP][8];

    // map blockIdx.x -> (expert e, m-block) over dynamic per-expert sizes
    int mblk = blockIdx.x;
    int e = 0;
    int base = 0, M = 0;
#pragma unroll
    for (int ee = 0; ee < NE; ++ee) {
        int b0 = offA[ee], b1 = offA[ee + 1];
        int nb = (b1 - b0 + 127) >> 7;
        if (e == ee && mblk >= nb) { mblk -= nb; e = ee + 1; }
        else if (e == ee) { base = b0; M = b1 - b0; }
    }
    if (e >= NE) return;

    const int m0 = mblk * 128;
    const int n0 = blockIdx.y * 128;
    const int t = threadIdx.x;
    const int w = t >> 6, lane = t & 63;
    const int wm = (w & 1) * 64, wn = (w >> 1) * 64;
    const int l15 = lane & 15, lg = lane >> 4;

    f32x4 acc[4][4];
#pragma unroll
    for (int i = 0; i < 4; ++i)
#pragma unroll
        for (int j = 0; j < 4; ++j) acc[i][j] = (f32x4){0.f, 0.f, 0.f, 0.f};

    const __hip_bfloat16* Ag = xsf + (size_t)(base + m0) * D_SZ;   // over-reads land in padded rows
    const __hip_bfloat16* Bg = pwb + (size_t)e * D_SZ * D_SZ + (size_t)n0 * D_SZ;

    for (int kt = 0; kt < D_SZ; kt += 64) {
        __syncthreads();
#pragma unroll
        for (int i = 0; i < 4; ++i) {
            int chunk = i * 256 + t;
            int row = chunk >> 3, kb = chunk & 7;
            *(uint4*)&As[kb][row][0] = *(const uint4*)(Ag + (size_t)row * D_SZ + kt + kb * 8);
            *(uint4*)&Bs[kb][row][0] = *(const uint4*)(Bg + (size_t)row * D_SZ + kt + kb * 8);
        }
        __syncthreads();
#pragma unroll
        for (int ks = 0; ks < 2; ++ks) {
            int kb = ks * 4 + lg;
            bf16x8 af[4], bfr[4];
#pragma unroll
            for (int ti = 0; ti < 4; ++ti) af[ti]  = *(const bf16x8*)&As[kb][wm + ti * 16 + l15][0];
#pragma unroll
            for (int tj = 0; tj < 4; ++tj) bfr[tj] = *(const bf16x8*)&Bs[kb][wn + tj * 16 + l15][0];
#pragma unroll
            for (int ti = 0; ti < 4; ++ti)
#pragma unroll
                for (int tj = 0; tj < 4; ++tj)
                    acc[ti][tj] = __builtin_amdgcn_mfma_f32_16x16x32_bf16(
                        af[ti], bfr[tj], acc[ti][tj], 0, 0, 0);
        }
    }

    // epilogue: atomicAdd (experts run concurrently; <=2 experts touch one out row)
    float pbv[4];
#pragma unroll
    for (int tj = 0; tj < 4; ++tj) pbv[tj] = pb[(size_t)e * D_SZ + n0 + wn + tj * 16 + l15];

#pragma unroll
    for (int ti = 0; ti < 4; ++ti) {
#pragma unroll
        for (int r = 0; r < 4; ++r) {
            int m = m0 + wm + ti * 16 + lg * 4 + r;
            if (m < M) {
                int slot = base + m;
                int brow = idx_list[slot];
                float wv = wgt_list[slot];
                float* orow = out + (size_t)brow * D_SZ + n0 + wn + l15;
#pragma unroll
                for (int tj = 0; tj < 4; ++tj)
                    atomicAdd(&orow[tj * 16], wv * (acc[ti][tj][r] + pbv[tj]));
            }
        }
    }
}

// ================= host launcher =================
extern "C" void kernel_launch(void* const* d_in, const int* in_sizes, int n_in,
                              void* d_out, int out_size, void* d_ws, size_t ws_size,
                              hipStream_t stream)
{
    const float* x   = (const float*)d_in[0];
    const float* gw1 = (const float*)d_in[1];
    const float* gb1 = (const float*)d_in[2];
    const float* gw2 = (const float*)d_in[3];
    const float* gb2 = (const float*)d_in[4];
    const float* pos = (const float*)d_in[5];
    const float* n1g = (const float*)d_in[6];
    const float* ipw = (const float*)d_in[7];
    const float* ipb = (const float*)d_in[8];
    const float* opw = (const float*)d_in[9];
    const float* opb = (const float*)d_in[10];
    const float* ls1 = (const float*)d_in[11];
    const float* n2g = (const float*)d_in[12];
    const float* fw1 = (const float*)d_in[13];
    const float* fb1 = (const float*)d_in[14];
    const float* fw2 = (const float*)d_in[15];
    const float* fb2 = (const float*)d_in[16];
    const float* ls2 = (const float*)d_in[17];
    const float* pw  = (const float*)d_in[18];
    const float* pb  = (const float*)d_in[19];

    float* out = (float*)d_out;

    char* ws = (char*)d_ws;
    int*   cnt      = (int*)(ws + 0);
    int*   cnt2     = (int*)(ws + 16);
    int*   offA     = (int*)(ws + 32);
    int*   topi     = (int*)(ws + WS_TOPI);
    float* topw     = (float*)(ws + WS_TOPW);
    int*   idx_list = (int*)(ws + WS_IDX);
    float* wgt_list = (float*)(ws + WS_WGT);
    __hip_bfloat16* xsf  = (__hip_bfloat16*)(ws + WS_XSF);
    __hip_bfloat16* pwb  = (__hip_bfloat16*)(ws + WS_PWB);
    __hip_bfloat16* ipwb = (__hip_bfloat16*)(ws + WS_IPWB);
    __hip_bfloat16* opwb = (__hip_bfloat16*)(ws + WS_OPWB);
    __hip_bfloat16* fw1b = (__hip_bfloat16*)(ws + WS_FW1B);
    __hip_bfloat16* fw2b = (__hip_bfloat16*)(ws + WS_FW2B);

    hipMemsetAsync(d_out, 0, (size_t)out_size * sizeof(float), stream);
    hipMemsetAsync(d_ws, 0, 64, stream);

    float* load_out = out + (size_t)B_SZ * D_SZ + 1;  // aux at B*D stays 0

    convert_pw<<<NE * D_SZ * D_SZ / (256 * 8), 256, 0, stream>>>(pw, pwb);
    convert_small<<<(N_IPW + N_OPW + N_FW1 + N_FW2) / (256 * 8), 256, 0, stream>>>(
        ipw, opw, fw1, fw2, ipwb, opwb, fw1b, fw2b);
    gate_kernel<<<B_SZ, 64, 0, stream>>>(x, gw1, gb1, gw2, gb2, cnt, topi, topw, load_out);
    offset_kernel<<<1, 64, 0, stream>>>(cnt, offA);
    scatter_kernel<<<B_SZ / 256, 256, 0, stream>>>(topi, topw, offA, cnt2, idx_list, wgt_list);
    expert_inner<<<2 * B_SZ, 256, 0, stream>>>(x, pos, n1g, ipwb, ipb, opwb, opb, ls1,
                                               n2g, fw1b, fb1, fw2b, fb2, ls2,
                                               offA, idx_list, xsf);
    expert_proj_mfma<<<dim3(2 * B_SZ / 128 + NE, D_SZ / 128), 256, 0, stream>>>(
        xsf, pwb, pb, offA, idx_list, wgt_list, out);
}

// Round 4
// 911.182 us; speedup vs baseline: 3.5628x; 1.2283x over previous
//
#include <hip/hip_runtime.h>
#include <hip/hip_bf16.h>
#include <math.h>

#define B_SZ 8192
#define D_SZ 1280
#define NE   4
#define NC   20
#define CD   64
#define NH   4
#define HD   16
#define FF   256

typedef __attribute__((ext_vector_type(8))) short bf16x8;
typedef __attribute__((ext_vector_type(4))) float f32x4;

// ---------------- workspace layout (bytes) ----------------
#define WS_TOPI   64
#define WS_TOPW   (64 + 2*B_SZ*4)
#define WS_IDX    (64 + 4*B_SZ*4)
#define WS_WGT    (64 + 6*B_SZ*4)
#define WS_XSF    (64 + 8*B_SZ*4)
#define XSF_ROWS  (2*B_SZ + 128)
#define WS_PWB    (WS_XSF + (size_t)XSF_ROWS * D_SZ * 2)
#define WS_IPWB   (WS_PWB  + (size_t)NE * D_SZ * D_SZ * 2)
#define WS_OPWB   (WS_IPWB + (size_t)NE * 192 * 64 * 2)
#define WS_FW1B   (WS_OPWB + (size_t)NE * 64 * 64 * 2)
#define WS_FW2B   (WS_FW1B + (size_t)NE * 256 * 64 * 2)

// ================= weight conversion =================
__global__ __launch_bounds__(256) void convert_pw(const float* __restrict__ pw,
                                                  __hip_bfloat16* __restrict__ pwb)
{
    size_t i = ((size_t)blockIdx.x * 256 + threadIdx.x) * 8;
    float4 a = *(const float4*)(pw + i);
    float4 b = *(const float4*)(pw + i + 4);
    __hip_bfloat16 h[8];
    h[0] = __float2bfloat16(a.x); h[1] = __float2bfloat16(a.y);
    h[2] = __float2bfloat16(a.z); h[3] = __float2bfloat16(a.w);
    h[4] = __float2bfloat16(b.x); h[5] = __float2bfloat16(b.y);
    h[6] = __float2bfloat16(b.z); h[7] = __float2bfloat16(b.w);
    *(uint4*)(pwb + i) = *(uint4*)h;
}

#define N_IPW (NE*192*64)
#define N_OPW (NE*64*64)
#define N_FW1 (NE*256*64)
#define N_FW2 (NE*64*256)
__global__ __launch_bounds__(256) void convert_small(
    const float* __restrict__ ipw, const float* __restrict__ opw,
    const float* __restrict__ fw1, const float* __restrict__ fw2,
    __hip_bfloat16* __restrict__ ipwb, __hip_bfloat16* __restrict__ opwb,
    __hip_bfloat16* __restrict__ fw1b, __hip_bfloat16* __restrict__ fw2b)
{
    size_t i = ((size_t)blockIdx.x * 256 + threadIdx.x) * 8;
    const float* src; __hip_bfloat16* dst; size_t off;
    if (i < N_IPW)                       { src = ipw; dst = ipwb; off = i; }
    else if (i < N_IPW + N_OPW)          { src = opw; dst = opwb; off = i - N_IPW; }
    else if (i < N_IPW + N_OPW + N_FW1)  { src = fw1; dst = fw1b; off = i - N_IPW - N_OPW; }
    else                                 { src = fw2; dst = fw2b; off = i - N_IPW - N_OPW - N_FW1; }
    float4 a = *(const float4*)(src + off);
    float4 b = *(const float4*)(src + off + 4);
    __hip_bfloat16 h[8];
    h[0] = __float2bfloat16(a.x); h[1] = __float2bfloat16(a.y);
    h[2] = __float2bfloat16(a.z); h[3] = __float2bfloat16(a.w);
    h[4] = __float2bfloat16(b.x); h[5] = __float2bfloat16(b.y);
    h[6] = __float2bfloat16(b.z); h[7] = __float2bfloat16(b.w);
    *(uint4*)(dst + off) = *(uint4*)h;
}

// ================= gate =================
__global__ __launch_bounds__(64) void gate_kernel(
    const float* __restrict__ x, const float* __restrict__ gw1, const float* __restrict__ gb1,
    const float* __restrict__ gw2, const float* __restrict__ gb2,
    int* __restrict__ cnt, int* __restrict__ topi, float* __restrict__ topw,
    float* __restrict__ load_out)
{
    const int b = blockIdx.x;
    const int lane = threadIdx.x;
    float acc[16];
#pragma unroll
    for (int j = 0; j < 16; ++j) acc[j] = 0.f;
    const float* xr = x + (size_t)b * D_SZ;
    for (int t = 0; t < NC; ++t) {
        float xv = xr[t * 64 + lane];
#pragma unroll
        for (int j = 0; j < 16; ++j) acc[j] += xv * gw1[j * D_SZ + t * 64 + lane];
    }
#pragma unroll
    for (int j = 0; j < 16; ++j) {
        acc[j] += __shfl_xor(acc[j], 32, 64);
        acc[j] += __shfl_xor(acc[j], 16, 64);
        acc[j] += __shfl_xor(acc[j], 8, 64);
        acc[j] += __shfl_xor(acc[j], 4, 64);
        acc[j] += __shfl_xor(acc[j], 2, 64);
        acc[j] += __shfl_xor(acc[j], 1, 64);
    }
    if (lane == 0) {
        float h[16];
#pragma unroll
        for (int j = 0; j < 16; ++j) h[j] = tanhf(acc[j] + gb1[j]);
        float l[4];
#pragma unroll
        for (int e = 0; e < 4; ++e) {
            float sv = gb2[e];
#pragma unroll
            for (int j = 0; j < 16; ++j) sv += h[j] * gw2[e * 16 + j];
            l[e] = sv;
        }
        float m = fmaxf(fmaxf(l[0], l[1]), fmaxf(l[2], l[3]));
        float p[4];
        float sum = 0.f;
#pragma unroll
        for (int e = 0; e < 4; ++e) { p[e] = expf(l[e] - m); sum += p[e]; }
#pragma unroll
        for (int e = 0; e < 4; ++e) p[e] /= sum;
        int i1 = 0;
#pragma unroll
        for (int e = 1; e < 4; ++e) if (p[e] > p[i1]) i1 = e;
        int i2 = (i1 == 0) ? 1 : 0;
#pragma unroll
        for (int e = 0; e < 4; ++e) if (e != i1 && p[e] > p[i2]) i2 = e;
        float s1 = p[i1], s2 = p[i2];
        float denom = s1 + s2 + 1e-6f;
        topi[b * 2 + 0] = i1;
        topi[b * 2 + 1] = i2;
        topw[b * 2 + 0] = s1 / denom;
        topw[b * 2 + 1] = s2 / denom;
        atomicAdd(&cnt[i1], 1);
        atomicAdd(&cnt[i2], 1);
        atomicAdd(&load_out[i1], 1.0f);
        atomicAdd(&load_out[i2], 1.0f);
    }
}

__global__ void offset_kernel(const int* __restrict__ cnt, int* __restrict__ offA)
{
    if (threadIdx.x == 0 && blockIdx.x == 0) {
        int a = 0;
#pragma unroll
        for (int e = 0; e < 4; ++e) { offA[e] = a; a += cnt[e]; }
        offA[4] = a;
    }
}

__global__ __launch_bounds__(256) void scatter_kernel(
    const int* __restrict__ topi, const float* __restrict__ topw,
    const int* __restrict__ offA, int* __restrict__ cnt2,
    int* __restrict__ idx_list, float* __restrict__ wgt_list)
{
    int b = blockIdx.x * 256 + threadIdx.x;
    if (b >= B_SZ) return;
#pragma unroll
    for (int k = 0; k < 2; ++k) {
        int e = topi[b * 2 + k];
        int pos = atomicAdd(&cnt2[e], 1);
        int s = offA[e] + pos;
        idx_list[s] = b;
        wgt_list[s] = topw[b * 2 + k];
    }
}

// ================= expert inner — full-MFMA (incl. attention) =================
// wave w = attention head. M=20 rows padded to 32. Pad-row garbage is finite
// (xnb pad rows zeroed) and row-confined; softmax max-subtract bounds exp even
// for garbage rows; P pad cols are exact zeros so V^T garbage cols annihilate.
__global__ __launch_bounds__(256) void expert_inner(
    const float* __restrict__ x, const float* __restrict__ pos,
    const float* __restrict__ n1g,
    const __hip_bfloat16* __restrict__ ipwb, const float* __restrict__ ipb,
    const __hip_bfloat16* __restrict__ opwb, const float* __restrict__ opb,
    const float* __restrict__ ls1, const float* __restrict__ n2g,
    const __hip_bfloat16* __restrict__ fw1b, const float* __restrict__ fb1,
    const __hip_bfloat16* __restrict__ fw2b, const float* __restrict__ fb2,
    const float* __restrict__ ls2,
    const int* __restrict__ offA, const int* __restrict__ idx_list,
    __hip_bfloat16* __restrict__ xsf)
{
    __shared__ float xs[NC][66];               // 5280 B residual (fp32)
    __shared__ __hip_bfloat16 xnb[32][72];     // 4608 B A-operand (norm1/attn-out/norm2)
    __shared__ __hip_bfloat16 qkb[32][136];    // 8704 B Q(0..63) K(64..127)
    __shared__ __hip_bfloat16 vtb[64][40];     // 5120 B V^T [h*16+d][kj pad32]
    __shared__ __hip_bfloat16 h1b[32][264];    // 16896 B ffn hidden; P[qi][h*32+kj] during attn
    // total 40608 B <= 40960 -> 4 blocks/CU

    const int t = threadIdx.x;
    const int w = t >> 6;
    const int lane = t & 63;
    const int l15 = lane & 15, lg = lane >> 4;
    const int s = blockIdx.x;
    const int e = (s >= offA[1]) + (s >= offA[2]) + (s >= offA[3]);
    const int b = idx_list[s];

    // stage 0: load + pos embed
    for (int idx = t; idx < D_SZ; idx += 256)
        xs[idx >> 6][idx & 63] = x[(size_t)b * D_SZ + idx] + pos[e * D_SZ + idx];
    __syncthreads();

    // stage 1: rmsnorm1 -> xnb (bf16) + zero pad rows 20..31
    {
        float g = n1g[e * CD + lane];
#pragma unroll
        for (int ic = 0; ic < 5; ++ic) {
            int c = w * 5 + ic;
            float v = xs[c][lane];
            float ss = v * v;
            ss += __shfl_xor(ss, 32, 64); ss += __shfl_xor(ss, 16, 64);
            ss += __shfl_xor(ss, 8, 64);  ss += __shfl_xor(ss, 4, 64);
            ss += __shfl_xor(ss, 2, 64);  ss += __shfl_xor(ss, 1, 64);
            float n = sqrtf(ss) * 0.125f + 1e-8f;
            xnb[c][lane] = __float2bfloat16(v / n * g);
        }
        __hip_bfloat16 z = __float2bfloat16(0.f);
        for (int i = t; i < 12 * 64; i += 256) xnb[20 + (i >> 6)][i & 63] = z;
    }
    __syncthreads();

    // stage 2: qkv = xn @ ipw^T + ipb (MFMA). Q,K -> qkb ; V -> vtb transposed.
    {
        bf16x8 af[2][2];
#pragma unroll
        for (int mt = 0; mt < 2; ++mt)
#pragma unroll
            for (int ks = 0; ks < 2; ++ks)
                af[mt][ks] = *(const bf16x8*)&xnb[mt * 16 + l15][ks * 32 + lg * 8];
#pragma unroll
        for (int i = 0; i < 3; ++i) {
            int tn = w * 3 + i;
            int n = tn * 16 + l15;
            f32x4 acc[2] = {{0,0,0,0},{0,0,0,0}};
#pragma unroll
            for (int ks = 0; ks < 2; ++ks) {
                bf16x8 bf = *(const bf16x8*)(ipwb + ((size_t)(e * 192 + n)) * 64 + ks * 32 + lg * 8);
#pragma unroll
                for (int mt = 0; mt < 2; ++mt)
                    acc[mt] = __builtin_amdgcn_mfma_f32_16x16x32_bf16(af[mt][ks], bf, acc[mt], 0, 0, 0);
            }
            float bias = ipb[e * 192 + n];
            if (tn < 8) {           // Q or K: store as-is
#pragma unroll
                for (int mt = 0; mt < 2; ++mt)
#pragma unroll
                    for (int r = 0; r < 4; ++r)
                        qkb[mt * 16 + lg * 4 + r][n] = __float2bfloat16(acc[mt][r] + bias);
            } else {                // V: store transposed into vtb[d_global][kj]
#pragma unroll
                for (int mt = 0; mt < 2; ++mt)
#pragma unroll
                    for (int r = 0; r < 4; ++r)
                        vtb[n - 128][mt * 16 + lg * 4 + r] = __float2bfloat16(acc[mt][r] + bias);
            }
        }
    }
    __syncthreads();

    // stage 3: attention via MFMA (wave w = head)
    {
        bf16x8 zf = {0,0,0,0,0,0,0,0};
        bf16x8 aq[2], bk[2];
#pragma unroll
        for (int mt = 0; mt < 2; ++mt)
            aq[mt] = (lg < 2) ? *(const bf16x8*)&qkb[mt * 16 + l15][w * 16 + lg * 8] : zf;
#pragma unroll
        for (int nt = 0; nt < 2; ++nt)
            bk[nt] = (lg < 2) ? *(const bf16x8*)&qkb[nt * 16 + l15][64 + w * 16 + lg * 8] : zf;
        f32x4 sacc[2][2];
#pragma unroll
        for (int mt = 0; mt < 2; ++mt)
#pragma unroll
            for (int nt = 0; nt < 2; ++nt)
                sacc[mt][nt] = __builtin_amdgcn_mfma_f32_16x16x32_bf16(
                    aq[mt], bk[nt], (f32x4){0,0,0,0}, 0, 0, 0);

        // softmax over kj (cols): row qi = mt*16+lg*4+r, col kj = nt*16+l15; valid kj<20
#pragma unroll
        for (int mt = 0; mt < 2; ++mt) {
#pragma unroll
            for (int r = 0; r < 4; ++r) {
                float v0 = sacc[mt][0][r] * 0.25f;                       // kj = l15 < 16 valid
                float v1 = (l15 < 4) ? sacc[mt][1][r] * 0.25f : -3.0e38f; // kj = 16+l15
                float mx = fmaxf(v0, v1);
                mx = fmaxf(mx, __shfl_xor(mx, 1, 64));
                mx = fmaxf(mx, __shfl_xor(mx, 2, 64));
                mx = fmaxf(mx, __shfl_xor(mx, 4, 64));
                mx = fmaxf(mx, __shfl_xor(mx, 8, 64));
                float e0 = __expf(v0 - mx);
                float e1 = (l15 < 4) ? __expf(v1 - mx) : 0.f;
                float sm = e0 + e1;
                sm += __shfl_xor(sm, 1, 64);
                sm += __shfl_xor(sm, 2, 64);
                sm += __shfl_xor(sm, 4, 64);
                sm += __shfl_xor(sm, 8, 64);
                float is = 1.0f / sm;                                    // sm >= 1
                int qi = mt * 16 + lg * 4 + r;
                h1b[qi][w * 32 + l15]      = __float2bfloat16(e0 * is);
                h1b[qi][w * 32 + 16 + l15] = __float2bfloat16(e1 * is);  // zero for l15>=4
            }
        }
        // PV: O[qi][d] = P @ V, B-operand = V^T (own-wave LDS data, in-order DS)
        bf16x8 bv = *(const bf16x8*)&vtb[w * 16 + l15][lg * 8];
#pragma unroll
        for (int mt = 0; mt < 2; ++mt) {
            bf16x8 ap = *(const bf16x8*)&h1b[mt * 16 + l15][w * 32 + lg * 8];
            f32x4 oacc = __builtin_amdgcn_mfma_f32_16x16x32_bf16(ap, bv, (f32x4){0,0,0,0}, 0, 0, 0);
#pragma unroll
            for (int r = 0; r < 4; ++r)
                xnb[mt * 16 + lg * 4 + r][w * 16 + l15] = __float2bfloat16(oacc[r]);
        }
    }
    __syncthreads();

    // stage 4: out_proj (MFMA) + residual: xs += ls1*(o @ opw^T + opb)
    {
        bf16x8 af[2][2];
#pragma unroll
        for (int mt = 0; mt < 2; ++mt)
#pragma unroll
            for (int ks = 0; ks < 2; ++ks)
                af[mt][ks] = *(const bf16x8*)&xnb[mt * 16 + l15][ks * 32 + lg * 8];
        int n = w * 16 + l15;
        f32x4 acc[2] = {{0,0,0,0},{0,0,0,0}};
#pragma unroll
        for (int ks = 0; ks < 2; ++ks) {
            bf16x8 bf = *(const bf16x8*)(opwb + ((size_t)(e * 64 + n)) * 64 + ks * 32 + lg * 8);
#pragma unroll
            for (int mt = 0; mt < 2; ++mt)
                acc[mt] = __builtin_amdgcn_mfma_f32_16x16x32_bf16(af[mt][ks], bf, acc[mt], 0, 0, 0);
        }
        float l1v = ls1[e * 64 + n], ob = opb[e * 64 + n];
#pragma unroll
        for (int mt = 0; mt < 2; ++mt)
#pragma unroll
            for (int r = 0; r < 4; ++r) {
                int m = mt * 16 + lg * 4 + r;
                if (m < NC) xs[m][n] += l1v * (acc[mt][r] + ob);
            }
    }
    __syncthreads();

    // stage 5: rmsnorm2 -> xnb (pad rows still zero from stage 1)
    {
        float g = n2g[e * CD + lane];
#pragma unroll
        for (int ic = 0; ic < 5; ++ic) {
            int c = w * 5 + ic;
            float v = xs[c][lane];
            float ss = v * v;
            ss += __shfl_xor(ss, 32, 64); ss += __shfl_xor(ss, 16, 64);
            ss += __shfl_xor(ss, 8, 64);  ss += __shfl_xor(ss, 4, 64);
            ss += __shfl_xor(ss, 2, 64);  ss += __shfl_xor(ss, 1, 64);
            float n = sqrtf(ss) * 0.125f + 1e-8f;
            xnb[c][lane] = __float2bfloat16(v / n * g);
        }
        // re-zero pad rows (attention wrote garbage there)
        __hip_bfloat16 z = __float2bfloat16(0.f);
        for (int i = t; i < 12 * 64; i += 256) xnb[20 + (i >> 6)][i & 63] = z;
    }
    __syncthreads();

    // stage 6: ffn1 (MFMA): h1 = relu(xn2 @ fw1^T + fb1)
    {
        bf16x8 af[2][2];
#pragma unroll
        for (int mt = 0; mt < 2; ++mt)
#pragma unroll
            for (int ks = 0; ks < 2; ++ks)
                af[mt][ks] = *(const bf16x8*)&xnb[mt * 16 + l15][ks * 32 + lg * 8];
#pragma unroll
        for (int i = 0; i < 4; ++i) {
            int n = (w * 4 + i) * 16 + l15;
            f32x4 acc[2] = {{0,0,0,0},{0,0,0,0}};
#pragma unroll
            for (int ks = 0; ks < 2; ++ks) {
                bf16x8 bf = *(const bf16x8*)(fw1b + ((size_t)(e * 256 + n)) * 64 + ks * 32 + lg * 8);
#pragma unroll
                for (int mt = 0; mt < 2; ++mt)
                    acc[mt] = __builtin_amdgcn_mfma_f32_16x16x32_bf16(af[mt][ks], bf, acc[mt], 0, 0, 0);
            }
            float b1 = fb1[e * 256 + n];
#pragma unroll
            for (int mt = 0; mt < 2; ++mt)
#pragma unroll
                for (int r = 0; r < 4; ++r)
                    h1b[mt * 16 + lg * 4 + r][n] = __float2bfloat16(fmaxf(acc[mt][r] + b1, 0.f));
        }
    }
    __syncthreads();

    // stage 7: ffn2 (MFMA, K=256): xs += ls2*(h1 @ fw2^T + fb2)
    {
        int n = w * 16 + l15;
        f32x4 acc[2] = {{0,0,0,0},{0,0,0,0}};
#pragma unroll
        for (int ks = 0; ks < 8; ++ks) {
            bf16x8 bf = *(const bf16x8*)(fw2b + ((size_t)(e * 64 + n)) * 256 + ks * 32 + lg * 8);
#pragma unroll
            for (int mt = 0; mt < 2; ++mt) {
                bf16x8 af = *(const bf16x8*)&h1b[mt * 16 + l15][ks * 32 + lg * 8];
                acc[mt] = __builtin_amdgcn_mfma_f32_16x16x32_bf16(af, bf, acc[mt], 0, 0, 0);
            }
        }
        float l2v = ls2[e * 64 + n], b2 = fb2[e * 64 + n];
#pragma unroll
        for (int mt = 0; mt < 2; ++mt)
#pragma unroll
            for (int r = 0; r < 4; ++r) {
                int m = mt * 16 + lg * 4 + r;
                if (m < NC) xs[m][n] += l2v * (acc[mt][r] + b2);
            }
    }
    __syncthreads();

    // stage 8: write xs (bf16)
    for (int idx = t; idx < D_SZ; idx += 256)
        xsf[(size_t)s * D_SZ + idx] = __float2bfloat16(xs[idx >> 6][idx & 63]);
}

// ================= final proj grouped GEMM — bf16 MFMA, all experts one launch =================
#define PROWP 130

__global__ __launch_bounds__(256) void expert_proj_mfma(
    const __hip_bfloat16* __restrict__ xsf, const __hip_bfloat16* __restrict__ pwb,
    const float* __restrict__ pb, const int* __restrict__ offA,
    const int* __restrict__ idx_list, const float* __restrict__ wgt_list,
    float* __restrict__ out)
{
    __shared__ short As[8][PROWP][8];
    __shared__ short Bs[8][PROWP][8];

    int mblk = blockIdx.x;
    int e = 0;
    int base = 0, M = 0;
#pragma unroll
    for (int ee = 0; ee < NE; ++ee) {
        int b0 = offA[ee], b1 = offA[ee + 1];
        int nb = (b1 - b0 + 127) >> 7;
        if (e == ee && mblk >= nb) { mblk -= nb; e = ee + 1; }
        else if (e == ee) { base = b0; M = b1 - b0; }
    }
    if (e >= NE) return;

    const int m0 = mblk * 128;
    const int n0 = blockIdx.y * 128;
    const int t = threadIdx.x;
    const int w = t >> 6, lane = t & 63;
    const int wm = (w & 1) * 64, wn = (w >> 1) * 64;
    const int l15 = lane & 15, lg = lane >> 4;

    f32x4 acc[4][4];
#pragma unroll
    for (int i = 0; i < 4; ++i)
#pragma unroll
        for (int j = 0; j < 4; ++j) acc[i][j] = (f32x4){0.f, 0.f, 0.f, 0.f};

    const __hip_bfloat16* Ag = xsf + (size_t)(base + m0) * D_SZ;
    const __hip_bfloat16* Bg = pwb + (size_t)e * D_SZ * D_SZ + (size_t)n0 * D_SZ;

    for (int kt = 0; kt < D_SZ; kt += 64) {
        __syncthreads();
#pragma unroll
        for (int i = 0; i < 4; ++i) {
            int chunk = i * 256 + t;
            int row = chunk >> 3, kb = chunk & 7;
            *(uint4*)&As[kb][row][0] = *(const uint4*)(Ag + (size_t)row * D_SZ + kt + kb * 8);
            *(uint4*)&Bs[kb][row][0] = *(const uint4*)(Bg + (size_t)row * D_SZ + kt + kb * 8);
        }
        __syncthreads();
#pragma unroll
        for (int ks = 0; ks < 2; ++ks) {
            int kb = ks * 4 + lg;
            bf16x8 af[4], bfr[4];
#pragma unroll
            for (int ti = 0; ti < 4; ++ti) af[ti]  = *(const bf16x8*)&As[kb][wm + ti * 16 + l15][0];
#pragma unroll
            for (int tj = 0; tj < 4; ++tj) bfr[tj] = *(const bf16x8*)&Bs[kb][wn + tj * 16 + l15][0];
#pragma unroll
            for (int ti = 0; ti < 4; ++ti)
#pragma unroll
                for (int tj = 0; tj < 4; ++tj)
                    acc[ti][tj] = __builtin_amdgcn_mfma_f32_16x16x32_bf16(
                        af[ti], bfr[tj], acc[ti][tj], 0, 0, 0);
        }
    }

    float pbv[4];
#pragma unroll
    for (int tj = 0; tj < 4; ++tj) pbv[tj] = pb[(size_t)e * D_SZ + n0 + wn + tj * 16 + l15];

#pragma unroll
    for (int ti = 0; ti < 4; ++ti) {
#pragma unroll
        for (int r = 0; r < 4; ++r) {
            int m = m0 + wm + ti * 16 + lg * 4 + r;
            if (m < M) {
                int slot = base + m;
                int brow = idx_list[slot];
                float wv = wgt_list[slot];
                float* orow = out + (size_t)brow * D_SZ + n0 + wn + l15;
#pragma unroll
                for (int tj = 0; tj < 4; ++tj)
                    atomicAdd(&orow[tj * 16], wv * (acc[ti][tj][r] + pbv[tj]));
            }
        }
    }
}

// ================= host launcher =================
extern "C" void kernel_launch(void* const* d_in, const int* in_sizes, int n_in,
                              void* d_out, int out_size, void* d_ws, size_t ws_size,
                              hipStream_t stream)
{
    const float* x   = (const float*)d_in[0];
    const float* gw1 = (const float*)d_in[1];
    const float* gb1 = (const float*)d_in[2];
    const float* gw2 = (const float*)d_in[3];
    const float* gb2 = (const float*)d_in[4];
    const float* pos = (const float*)d_in[5];
    const float* n1g = (const float*)d_in[6];
    const float* ipw = (const float*)d_in[7];
    const float* ipb = (const float*)d_in[8];
    const float* opw = (const float*)d_in[9];
    const float* opb = (const float*)d_in[10];
    const float* ls1 = (const float*)d_in[11];
    const float* n2g = (const float*)d_in[12];
    const float* fw1 = (const float*)d_in[13];
    const float* fb1 = (const float*)d_in[14];
    const float* fw2 = (const float*)d_in[15];
    const float* fb2 = (const float*)d_in[16];
    const float* ls2 = (const float*)d_in[17];
    const float* pw  = (const float*)d_in[18];
    const float* pb  = (const float*)d_in[19];

    float* out = (float*)d_out;

    char* ws = (char*)d_ws;
    int*   cnt      = (int*)(ws + 0);
    int*   cnt2     = (int*)(ws + 16);
    int*   offA     = (int*)(ws + 32);
    int*   topi     = (int*)(ws + WS_TOPI);
    float* topw     = (float*)(ws + WS_TOPW);
    int*   idx_list = (int*)(ws + WS_IDX);
    float* wgt_list = (float*)(ws + WS_WGT);
    __hip_bfloat16* xsf  = (__hip_bfloat16*)(ws + WS_XSF);
    __hip_bfloat16* pwb  = (__hip_bfloat16*)(ws + WS_PWB);
    __hip_bfloat16* ipwb = (__hip_bfloat16*)(ws + WS_IPWB);
    __hip_bfloat16* opwb = (__hip_bfloat16*)(ws + WS_OPWB);
    __hip_bfloat16* fw1b = (__hip_bfloat16*)(ws + WS_FW1B);
    __hip_bfloat16* fw2b = (__hip_bfloat16*)(ws + WS_FW2B);

    hipMemsetAsync(d_out, 0, (size_t)out_size * sizeof(float), stream);
    hipMemsetAsync(d_ws, 0, 64, stream);

    float* load_out = out + (size_t)B_SZ * D_SZ + 1;  // aux at B*D stays 0

    convert_pw<<<NE * D_SZ * D_SZ / (256 * 8), 256, 0, stream>>>(pw, pwb);
    convert_small<<<(N_IPW + N_OPW + N_FW1 + N_FW2) / (256 * 8), 256, 0, stream>>>(
        ipw, opw, fw1, fw2, ipwb, opwb, fw1b, fw2b);
    gate_kernel<<<B_SZ, 64, 0, stream>>>(x, gw1, gb1, gw2, gb2, cnt, topi, topw, load_out);
    offset_kernel<<<1, 64, 0, stream>>>(cnt, offA);
    scatter_kernel<<<B_SZ / 256, 256, 0, stream>>>(topi, topw, offA, cnt2, idx_list, wgt_list);
    expert_inner<<<2 * B_SZ, 256, 0, stream>>>(x, pos, n1g, ipwb, ipb, opwb, opb, ls1,
                                               n2g, fw1b, fb1, fw2b, fb2, ls2,
                                               offA, idx_list, xsf);
    expert_proj_mfma<<<dim3(2 * B_SZ / 128 + NE, D_SZ / 128), 256, 0, stream>>>(
        xsf, pwb, pb, offA, idx_list, wgt_list, out);
}

// Round 5
// 562.304 us; speedup vs baseline: 5.7733x; 1.6204x over previous
//
#include <hip/hip_runtime.h>
#include <hip/hip_bf16.h>
#include <math.h>

#define B_SZ 8192
#define D_SZ 1280
#define NE   4
#define NC   20
#define CD   64
#define NH   4
#define HD   16
#define FF   256

typedef __attribute__((ext_vector_type(8))) short bf16x8;
typedef __attribute__((ext_vector_type(4))) float f32x4;

// ---------------- workspace layout (bytes) ----------------
// header: cnt[4]@0, pcnt[16]@16, offA[8]@80, poff[20]@112  (memset first 256 B)
#define WS_TOPI   256
#define WS_TOPW   (WS_TOPI + 2*B_SZ*4)
#define WS_IDX    (WS_TOPW + 2*B_SZ*4)
#define WS_WGT    (WS_IDX  + 2*B_SZ*4)
#define WS_ER0    (WS_WGT  + 2*B_SZ*4)
#define WS_ER1    (WS_ER0  + B_SZ*4)
#define WS_PRK    (WS_ER1  + B_SZ*4)
#define WS_BBE    (WS_PRK  + B_SZ*4)
#define WS_BBP    (WS_BBE  + 32*4*4)
#define WS_PRA    (WS_BBP  + 32*16*4)
#define WS_PRB    (WS_PRA  + (B_SZ+128)*4)
#define WS_PW1    (WS_PRB  + (B_SZ+128)*4)
#define WS_PW2    (WS_PW1  + (B_SZ+128)*4)
#define WS_PRW    (WS_PW2  + (B_SZ+128)*4)
#define WS_XSF    532480
#define XSF_ROWS  (2*B_SZ + 128)
#define WS_PWB    (WS_XSF + (size_t)XSF_ROWS * D_SZ * 2)
#define WS_IPWB   (WS_PWB  + (size_t)NE * D_SZ * D_SZ * 2)
#define WS_OPWB   (WS_IPWB + (size_t)NE * 192 * 64 * 2)
#define WS_FW1B   (WS_OPWB + (size_t)NE * 64 * 64 * 2)
#define WS_FW2B   (WS_FW1B + (size_t)NE * 256 * 64 * 2)

// ================= weight conversion =================
__global__ __launch_bounds__(256) void convert_pw(const float* __restrict__ pw,
                                                  __hip_bfloat16* __restrict__ pwb)
{
    size_t i = ((size_t)blockIdx.x * 256 + threadIdx.x) * 8;
    float4 a = *(const float4*)(pw + i);
    float4 b = *(const float4*)(pw + i + 4);
    __hip_bfloat16 h[8];
    h[0] = __float2bfloat16(a.x); h[1] = __float2bfloat16(a.y);
    h[2] = __float2bfloat16(a.z); h[3] = __float2bfloat16(a.w);
    h[4] = __float2bfloat16(b.x); h[5] = __float2bfloat16(b.y);
    h[6] = __float2bfloat16(b.z); h[7] = __float2bfloat16(b.w);
    *(uint4*)(pwb + i) = *(uint4*)h;
}

#define N_IPW (NE*192*64)
#define N_OPW (NE*64*64)
#define N_FW1 (NE*256*64)
#define N_FW2 (NE*64*256)
__global__ __launch_bounds__(256) void convert_small(
    const float* __restrict__ ipw, const float* __restrict__ opw,
    const float* __restrict__ fw1, const float* __restrict__ fw2,
    __hip_bfloat16* __restrict__ ipwb, __hip_bfloat16* __restrict__ opwb,
    __hip_bfloat16* __restrict__ fw1b, __hip_bfloat16* __restrict__ fw2b)
{
    size_t i = ((size_t)blockIdx.x * 256 + threadIdx.x) * 8;
    const float* src; __hip_bfloat16* dst; size_t off;
    if (i < N_IPW)                       { src = ipw; dst = ipwb; off = i; }
    else if (i < N_IPW + N_OPW)          { src = opw; dst = opwb; off = i - N_IPW; }
    else if (i < N_IPW + N_OPW + N_FW1)  { src = fw1; dst = fw1b; off = i - N_IPW - N_OPW; }
    else                                 { src = fw2; dst = fw2b; off = i - N_IPW - N_OPW - N_FW1; }
    float4 a = *(const float4*)(src + off);
    float4 b = *(const float4*)(src + off + 4);
    __hip_bfloat16 h[8];
    h[0] = __float2bfloat16(a.x); h[1] = __float2bfloat16(a.y);
    h[2] = __float2bfloat16(a.z); h[3] = __float2bfloat16(a.w);
    h[4] = __float2bfloat16(b.x); h[5] = __float2bfloat16(b.y);
    h[6] = __float2bfloat16(b.z); h[7] = __float2bfloat16(b.w);
    *(uint4*)(dst + off) = *(uint4*)h;
}

// ================= gate (no atomics) =================
__global__ __launch_bounds__(64) void gate_kernel(
    const float* __restrict__ x, const float* __restrict__ gw1, const float* __restrict__ gb1,
    const float* __restrict__ gw2, const float* __restrict__ gb2,
    int* __restrict__ topi, float* __restrict__ topw)
{
    const int b = blockIdx.x;
    const int lane = threadIdx.x;
    float acc[16];
#pragma unroll
    for (int j = 0; j < 16; ++j) acc[j] = 0.f;
    const float* xr = x + (size_t)b * D_SZ;
    for (int t = 0; t < NC; ++t) {
        float xv = xr[t * 64 + lane];
#pragma unroll
        for (int j = 0; j < 16; ++j) acc[j] += xv * gw1[j * D_SZ + t * 64 + lane];
    }
#pragma unroll
    for (int j = 0; j < 16; ++j) {
        acc[j] += __shfl_xor(acc[j], 32, 64);
        acc[j] += __shfl_xor(acc[j], 16, 64);
        acc[j] += __shfl_xor(acc[j], 8, 64);
        acc[j] += __shfl_xor(acc[j], 4, 64);
        acc[j] += __shfl_xor(acc[j], 2, 64);
        acc[j] += __shfl_xor(acc[j], 1, 64);
    }
    if (lane == 0) {
        float h[16];
#pragma unroll
        for (int j = 0; j < 16; ++j) h[j] = tanhf(acc[j] + gb1[j]);
        float l[4];
#pragma unroll
        for (int e = 0; e < 4; ++e) {
            float sv = gb2[e];
#pragma unroll
            for (int j = 0; j < 16; ++j) sv += h[j] * gw2[e * 16 + j];
            l[e] = sv;
        }
        float m = fmaxf(fmaxf(l[0], l[1]), fmaxf(l[2], l[3]));
        float p[4];
        float sum = 0.f;
#pragma unroll
        for (int e = 0; e < 4; ++e) { p[e] = expf(l[e] - m); sum += p[e]; }
#pragma unroll
        for (int e = 0; e < 4; ++e) p[e] /= sum;
        int i1 = 0;
#pragma unroll
        for (int e = 1; e < 4; ++e) if (p[e] > p[i1]) i1 = e;
        int i2 = (i1 == 0) ? 1 : 0;
#pragma unroll
        for (int e = 0; e < 4; ++e) if (e != i1 && p[e] > p[i2]) i2 = e;
        float s1 = p[i1], s2 = p[i2];
        float denom = s1 + s2 + 1e-6f;
        topi[b * 2 + 0] = i1;
        topi[b * 2 + 1] = i2;
        topw[b * 2 + 0] = s1 / denom;
        topw[b * 2 + 1] = s2 / denom;
    }
}

// ================= routing: block-aggregated count =================
__global__ __launch_bounds__(256) void count_kernel(
    const int* __restrict__ topi,
    int* __restrict__ cnt, int* __restrict__ pcnt,
    int* __restrict__ er0, int* __restrict__ er1, int* __restrict__ prk,
    int* __restrict__ bbe, int* __restrict__ bbp)
{
    __shared__ int he[4], hp[16];
    const int t = threadIdx.x;
    const int blk = blockIdx.x;
    const int b = blk * 256 + t;
    if (t < 4) he[t] = 0;
    if (t < 16) hp[t] = 0;
    __syncthreads();
    int e0 = topi[b * 2], e1 = topi[b * 2 + 1];
    er0[b] = atomicAdd(&he[e0], 1);
    er1[b] = atomicAdd(&he[e1], 1);
    prk[b] = atomicAdd(&hp[e0 * 4 + e1], 1);
    __syncthreads();
    if (t < 4)  bbe[blk * 4 + t]  = atomicAdd(&cnt[t], he[t]);
    if (t < 16) bbp[blk * 16 + t] = atomicAdd(&pcnt[t], hp[t]);
}

__global__ void offsets_kernel(const int* __restrict__ cnt, const int* __restrict__ pcnt,
                               int* __restrict__ offA, int* __restrict__ poff,
                               float* __restrict__ load_out)
{
    if (threadIdx.x == 0 && blockIdx.x == 0) {
        int a = 0;
#pragma unroll
        for (int e = 0; e < 4; ++e) { offA[e] = a; a += cnt[e]; }
        offA[4] = a;
        int q = 0;
#pragma unroll
        for (int p = 0; p < 16; ++p) { poff[p] = q; q += pcnt[p]; }
        poff[16] = q;
#pragma unroll
        for (int e = 0; e < 4; ++e) load_out[e] = (float)cnt[e];
    }
}

__global__ __launch_bounds__(256) void fill_kernel(
    const int* __restrict__ topi, const float* __restrict__ topw,
    const int* __restrict__ offA, const int* __restrict__ poff,
    const int* __restrict__ er0, const int* __restrict__ er1, const int* __restrict__ prk,
    const int* __restrict__ bbe, const int* __restrict__ bbp,
    int* __restrict__ idx_list, float* __restrict__ wgt_list,
    int* __restrict__ prA, int* __restrict__ prB,
    float* __restrict__ pw1, float* __restrict__ pw2, int* __restrict__ prow)
{
    const int b = blockIdx.x * 256 + threadIdx.x;
    const int blk = blockIdx.x;
    int e0 = topi[b * 2], e1 = topi[b * 2 + 1];
    float w0 = topw[b * 2], w1 = topw[b * 2 + 1];
    int slot0 = offA[e0] + bbe[blk * 4 + e0] + er0[b];
    int slot1 = offA[e1] + bbe[blk * 4 + e1] + er1[b];
    idx_list[slot0] = b; wgt_list[slot0] = w0;
    idx_list[slot1] = b; wgt_list[slot1] = w1;
    int p = e0 * 4 + e1;
    int pos = poff[p] + bbp[blk * 16 + p] + prk[b];
    prA[pos] = slot0; prB[pos] = slot1;
    pw1[pos] = w0; pw2[pos] = w1; prow[pos] = b;
}

// ================= expert inner — full-MFMA (incl. attention) =================
// wave w = attention head. M=20 rows padded to 32. xsf output is pre-scaled by
// the combine weight (w*(A@B) == (w*A)@B), so proj needs no per-row weighting.
__global__ __launch_bounds__(256) void expert_inner(
    const float* __restrict__ x, const float* __restrict__ pos,
    const float* __restrict__ n1g,
    const __hip_bfloat16* __restrict__ ipwb, const float* __restrict__ ipb,
    const __hip_bfloat16* __restrict__ opwb, const float* __restrict__ opb,
    const float* __restrict__ ls1, const float* __restrict__ n2g,
    const __hip_bfloat16* __restrict__ fw1b, const float* __restrict__ fb1,
    const __hip_bfloat16* __restrict__ fw2b, const float* __restrict__ fb2,
    const float* __restrict__ ls2,
    const int* __restrict__ offA, const int* __restrict__ idx_list,
    const float* __restrict__ wgt_list,
    __hip_bfloat16* __restrict__ xsf)
{
    __shared__ float xs[NC][66];
    __shared__ __hip_bfloat16 xnb[32][72];
    __shared__ __hip_bfloat16 qkb[32][136];    // Q(0..63) K(64..127)
    __shared__ __hip_bfloat16 vtb[64][40];     // V^T [h*16+d][kj pad32]
    __shared__ __hip_bfloat16 h1b[32][264];    // ffn hidden; P[qi][h*32+kj] during attn

    const int t = threadIdx.x;
    const int w = t >> 6;
    const int lane = t & 63;
    const int l15 = lane & 15, lg = lane >> 4;
    const int s = blockIdx.x;
    const int e = (s >= offA[1]) + (s >= offA[2]) + (s >= offA[3]);
    const int b = idx_list[s];
    const float wgt = wgt_list[s];

    // stage 0: load + pos embed
    for (int idx = t; idx < D_SZ; idx += 256)
        xs[idx >> 6][idx & 63] = x[(size_t)b * D_SZ + idx] + pos[e * D_SZ + idx];
    __syncthreads();

    // stage 1: rmsnorm1 -> xnb (bf16) + zero pad rows 20..31
    {
        float g = n1g[e * CD + lane];
#pragma unroll
        for (int ic = 0; ic < 5; ++ic) {
            int c = w * 5 + ic;
            float v = xs[c][lane];
            float ss = v * v;
            ss += __shfl_xor(ss, 32, 64); ss += __shfl_xor(ss, 16, 64);
            ss += __shfl_xor(ss, 8, 64);  ss += __shfl_xor(ss, 4, 64);
            ss += __shfl_xor(ss, 2, 64);  ss += __shfl_xor(ss, 1, 64);
            float n = sqrtf(ss) * 0.125f + 1e-8f;
            xnb[c][lane] = __float2bfloat16(v / n * g);
        }
        __hip_bfloat16 z = __float2bfloat16(0.f);
        for (int i = t; i < 12 * 64; i += 256) xnb[20 + (i >> 6)][i & 63] = z;
    }
    __syncthreads();

    // stage 2: qkv = xn @ ipw^T + ipb (MFMA). Q,K -> qkb ; V -> vtb transposed.
    {
        bf16x8 af[2][2];
#pragma unroll
        for (int mt = 0; mt < 2; ++mt)
#pragma unroll
            for (int ks = 0; ks < 2; ++ks)
                af[mt][ks] = *(const bf16x8*)&xnb[mt * 16 + l15][ks * 32 + lg * 8];
#pragma unroll
        for (int i = 0; i < 3; ++i) {
            int tn = w * 3 + i;
            int n = tn * 16 + l15;
            f32x4 acc[2] = {{0,0,0,0},{0,0,0,0}};
#pragma unroll
            for (int ks = 0; ks < 2; ++ks) {
                bf16x8 bf = *(const bf16x8*)(ipwb + ((size_t)(e * 192 + n)) * 64 + ks * 32 + lg * 8);
#pragma unroll
                for (int mt = 0; mt < 2; ++mt)
                    acc[mt] = __builtin_amdgcn_mfma_f32_16x16x32_bf16(af[mt][ks], bf, acc[mt], 0, 0, 0);
            }
            float bias = ipb[e * 192 + n];
            if (tn < 8) {
#pragma unroll
                for (int mt = 0; mt < 2; ++mt)
#pragma unroll
                    for (int r = 0; r < 4; ++r)
                        qkb[mt * 16 + lg * 4 + r][n] = __float2bfloat16(acc[mt][r] + bias);
            } else {
#pragma unroll
                for (int mt = 0; mt < 2; ++mt)
#pragma unroll
                    for (int r = 0; r < 4; ++r)
                        vtb[n - 128][mt * 16 + lg * 4 + r] = __float2bfloat16(acc[mt][r] + bias);
            }
        }
    }
    __syncthreads();

    // stage 3: attention via MFMA (wave w = head)
    {
        bf16x8 zf = {0,0,0,0,0,0,0,0};
        bf16x8 aq[2], bk[2];
#pragma unroll
        for (int mt = 0; mt < 2; ++mt)
            aq[mt] = (lg < 2) ? *(const bf16x8*)&qkb[mt * 16 + l15][w * 16 + lg * 8] : zf;
#pragma unroll
        for (int nt = 0; nt < 2; ++nt)
            bk[nt] = (lg < 2) ? *(const bf16x8*)&qkb[nt * 16 + l15][64 + w * 16 + lg * 8] : zf;
        f32x4 sacc[2][2];
#pragma unroll
        for (int mt = 0; mt < 2; ++mt)
#pragma unroll
            for (int nt = 0; nt < 2; ++nt)
                sacc[mt][nt] = __builtin_amdgcn_mfma_f32_16x16x32_bf16(
                    aq[mt], bk[nt], (f32x4){0,0,0,0}, 0, 0, 0);

#pragma unroll
        for (int mt = 0; mt < 2; ++mt) {
#pragma unroll
            for (int r = 0; r < 4; ++r) {
                float v0 = sacc[mt][0][r] * 0.25f;
                float v1 = (l15 < 4) ? sacc[mt][1][r] * 0.25f : -3.0e38f;
                float mx = fmaxf(v0, v1);
                mx = fmaxf(mx, __shfl_xor(mx, 1, 64));
                mx = fmaxf(mx, __shfl_xor(mx, 2, 64));
                mx = fmaxf(mx, __shfl_xor(mx, 4, 64));
                mx = fmaxf(mx, __shfl_xor(mx, 8, 64));
                float e0 = __expf(v0 - mx);
                float e1 = (l15 < 4) ? __expf(v1 - mx) : 0.f;
                float sm = e0 + e1;
                sm += __shfl_xor(sm, 1, 64);
                sm += __shfl_xor(sm, 2, 64);
                sm += __shfl_xor(sm, 4, 64);
                sm += __shfl_xor(sm, 8, 64);
                float is = 1.0f / sm;
                int qi = mt * 16 + lg * 4 + r;
                h1b[qi][w * 32 + l15]      = __float2bfloat16(e0 * is);
                h1b[qi][w * 32 + 16 + l15] = __float2bfloat16(e1 * is);
            }
        }
        bf16x8 bv = *(const bf16x8*)&vtb[w * 16 + l15][lg * 8];
#pragma unroll
        for (int mt = 0; mt < 2; ++mt) {
            bf16x8 ap = *(const bf16x8*)&h1b[mt * 16 + l15][w * 32 + lg * 8];
            f32x4 oacc = __builtin_amdgcn_mfma_f32_16x16x32_bf16(ap, bv, (f32x4){0,0,0,0}, 0, 0, 0);
#pragma unroll
            for (int r = 0; r < 4; ++r)
                xnb[mt * 16 + lg * 4 + r][w * 16 + l15] = __float2bfloat16(oacc[r]);
        }
    }
    __syncthreads();

    // stage 4: out_proj (MFMA) + residual
    {
        bf16x8 af[2][2];
#pragma unroll
        for (int mt = 0; mt < 2; ++mt)
#pragma unroll
            for (int ks = 0; ks < 2; ++ks)
                af[mt][ks] = *(const bf16x8*)&xnb[mt * 16 + l15][ks * 32 + lg * 8];
        int n = w * 16 + l15;
        f32x4 acc[2] = {{0,0,0,0},{0,0,0,0}};
#pragma unroll
        for (int ks = 0; ks < 2; ++ks) {
            bf16x8 bf = *(const bf16x8*)(opwb + ((size_t)(e * 64 + n)) * 64 + ks * 32 + lg * 8);
#pragma unroll
            for (int mt = 0; mt < 2; ++mt)
                acc[mt] = __builtin_amdgcn_mfma_f32_16x16x32_bf16(af[mt][ks], bf, acc[mt], 0, 0, 0);
        }
        float l1v = ls1[e * 64 + n], ob = opb[e * 64 + n];
#pragma unroll
        for (int mt = 0; mt < 2; ++mt)
#pragma unroll
            for (int r = 0; r < 4; ++r) {
                int m = mt * 16 + lg * 4 + r;
                if (m < NC) xs[m][n] += l1v * (acc[mt][r] + ob);
            }
    }
    __syncthreads();

    // stage 5: rmsnorm2 -> xnb
    {
        float g = n2g[e * CD + lane];
#pragma unroll
        for (int ic = 0; ic < 5; ++ic) {
            int c = w * 5 + ic;
            float v = xs[c][lane];
            float ss = v * v;
            ss += __shfl_xor(ss, 32, 64); ss += __shfl_xor(ss, 16, 64);
            ss += __shfl_xor(ss, 8, 64);  ss += __shfl_xor(ss, 4, 64);
            ss += __shfl_xor(ss, 2, 64);  ss += __shfl_xor(ss, 1, 64);
            float n = sqrtf(ss) * 0.125f + 1e-8f;
            xnb[c][lane] = __float2bfloat16(v / n * g);
        }
        __hip_bfloat16 z = __float2bfloat16(0.f);
        for (int i = t; i < 12 * 64; i += 256) xnb[20 + (i >> 6)][i & 63] = z;
    }
    __syncthreads();

    // stage 6: ffn1 (MFMA)
    {
        bf16x8 af[2][2];
#pragma unroll
        for (int mt = 0; mt < 2; ++mt)
#pragma unroll
            for (int ks = 0; ks < 2; ++ks)
                af[mt][ks] = *(const bf16x8*)&xnb[mt * 16 + l15][ks * 32 + lg * 8];
#pragma unroll
        for (int i = 0; i < 4; ++i) {
            int n = (w * 4 + i) * 16 + l15;
            f32x4 acc[2] = {{0,0,0,0},{0,0,0,0}};
#pragma unroll
            for (int ks = 0; ks < 2; ++ks) {
                bf16x8 bf = *(const bf16x8*)(fw1b + ((size_t)(e * 256 + n)) * 64 + ks * 32 + lg * 8);
#pragma unroll
                for (int mt = 0; mt < 2; ++mt)
                    acc[mt] = __builtin_amdgcn_mfma_f32_16x16x32_bf16(af[mt][ks], bf, acc[mt], 0, 0, 0);
            }
            float b1 = fb1[e * 256 + n];
#pragma unroll
            for (int mt = 0; mt < 2; ++mt)
#pragma unroll
                for (int r = 0; r < 4; ++r)
                    h1b[mt * 16 + lg * 4 + r][n] = __float2bfloat16(fmaxf(acc[mt][r] + b1, 0.f));
        }
    }
    __syncthreads();

    // stage 7: ffn2 (MFMA, K=256)
    {
        int n = w * 16 + l15;
        f32x4 acc[2] = {{0,0,0,0},{0,0,0,0}};
#pragma unroll
        for (int ks = 0; ks < 8; ++ks) {
            bf16x8 bf = *(const bf16x8*)(fw2b + ((size_t)(e * 64 + n)) * 256 + ks * 32 + lg * 8);
#pragma unroll
            for (int mt = 0; mt < 2; ++mt) {
                bf16x8 af = *(const bf16x8*)&h1b[mt * 16 + l15][ks * 32 + lg * 8];
                acc[mt] = __builtin_amdgcn_mfma_f32_16x16x32_bf16(af, bf, acc[mt], 0, 0, 0);
            }
        }
        float l2v = ls2[e * 64 + n], b2 = fb2[e * 64 + n];
#pragma unroll
        for (int mt = 0; mt < 2; ++mt)
#pragma unroll
            for (int r = 0; r < 4; ++r) {
                int m = mt * 16 + lg * 4 + r;
                if (m < NC) xs[m][n] += l2v * (acc[mt][r] + b2);
            }
    }
    __syncthreads();

    // stage 8: write xs pre-scaled by combine weight (bf16)
    for (int idx = t; idx < D_SZ; idx += 256)
        xsf[(size_t)s * D_SZ + idx] = __float2bfloat16(wgt * xs[idx >> 6][idx & 63]);
}

// ================= final proj — pair-bucketed, atomic-free =================
// out[b] = (w1 A1)B_e1 + (w2 A2)B_e2 + w1 pb[e1] + w2 pb[e2]; A pre-scaled.
// Rows bucketed by ordered expert pair -> one plain store per out element.
#define PROWP 130

__global__ __launch_bounds__(256) void proj_pair(
    const __hip_bfloat16* __restrict__ xsf, const __hip_bfloat16* __restrict__ pwb,
    const float* __restrict__ pb, const int* __restrict__ poff,
    const int* __restrict__ prA, const int* __restrict__ prB,
    const float* __restrict__ pw1, const float* __restrict__ pw2,
    const int* __restrict__ prow, float* __restrict__ out)
{
    __shared__ short As[8][PROWP][8];
    __shared__ short Bs[8][PROWP][8];
    __shared__ int   sSlot[2][128];
    __shared__ float sW[2][128];
    __shared__ int   sRow[128];

    int mblk = blockIdx.x;
    int p = 0, base = 0, M = 0;
#pragma unroll
    for (int pp = 0; pp < 16; ++pp) {
        int b0 = poff[pp], b1 = poff[pp + 1];
        int nb = (b1 - b0 + 127) >> 7;
        if (p == pp && mblk >= nb) { mblk -= nb; p = pp + 1; }
        else if (p == pp) { base = b0; M = b1 - b0; }
    }
    if (p >= 16) return;
    const int ea = p >> 2, eb = p & 3;

    const int m0 = mblk * 128;
    const int n0 = blockIdx.y * 128;
    const int t = threadIdx.x;
    const int w = t >> 6, lane = t & 63;
    const int wm = (w & 1) * 64, wn = (w >> 1) * 64;
    const int l15 = lane & 15, lg = lane >> 4;

    if (t < 128) {
        int posn = base + m0 + t;
        int sa = prA[posn], sb = prB[posn];
        sSlot[0][t] = min(max(sa, 0), 2 * B_SZ);
        sSlot[1][t] = min(max(sb, 0), 2 * B_SZ);
        sW[0][t] = pw1[posn]; sW[1][t] = pw2[posn];
        sRow[t] = prow[posn];
    }
    __syncthreads();

    f32x4 acc[4][4];
#pragma unroll
    for (int i = 0; i < 4; ++i)
#pragma unroll
        for (int j = 0; j < 4; ++j) acc[i][j] = (f32x4){0.f, 0.f, 0.f, 0.f};

    const int arow0 = t >> 3;          // this thread's 4 staging rows: arow0 + 32*i
    const int akb = t & 7;

#pragma unroll
    for (int ph = 0; ph < 2; ++ph) {
        const __hip_bfloat16* Bg = pwb + (size_t)(ph ? eb : ea) * D_SZ * D_SZ + (size_t)n0 * D_SZ;
        int aslot[4];
#pragma unroll
        for (int i = 0; i < 4; ++i) aslot[i] = sSlot[ph][arow0 + 32 * i];

        for (int kt = 0; kt < D_SZ; kt += 64) {
            __syncthreads();
#pragma unroll
            for (int i = 0; i < 4; ++i) {
                int row = arow0 + 32 * i;
                *(uint4*)&As[akb][row][0] =
                    *(const uint4*)(xsf + (size_t)aslot[i] * D_SZ + kt + akb * 8);
                *(uint4*)&Bs[akb][row][0] =
                    *(const uint4*)(Bg + (size_t)row * D_SZ + kt + akb * 8);
            }
            __syncthreads();
#pragma unroll
            for (int ks = 0; ks < 2; ++ks) {
                int kb = ks * 4 + lg;
                bf16x8 af[4], bfr[4];
#pragma unroll
                for (int ti = 0; ti < 4; ++ti) af[ti]  = *(const bf16x8*)&As[kb][wm + ti * 16 + l15][0];
#pragma unroll
                for (int tj = 0; tj < 4; ++tj) bfr[tj] = *(const bf16x8*)&Bs[kb][wn + tj * 16 + l15][0];
#pragma unroll
                for (int ti = 0; ti < 4; ++ti)
#pragma unroll
                    for (int tj = 0; tj < 4; ++tj)
                        acc[ti][tj] = __builtin_amdgcn_mfma_f32_16x16x32_bf16(
                            af[ti], bfr[tj], acc[ti][tj], 0, 0, 0);
            }
        }
    }

    float pbva[4], pbvb[4];
#pragma unroll
    for (int tj = 0; tj < 4; ++tj) {
        int nc = n0 + wn + tj * 16 + l15;
        pbva[tj] = pb[(size_t)ea * D_SZ + nc];
        pbvb[tj] = pb[(size_t)eb * D_SZ + nc];
    }

#pragma unroll
    for (int ti = 0; ti < 4; ++ti) {
#pragma unroll
        for (int r = 0; r < 4; ++r) {
            int m = wm + ti * 16 + lg * 4 + r;
            if (m0 + m < M) {
                float w1 = sW[0][m], w2 = sW[1][m];
                float* orow = out + (size_t)sRow[m] * D_SZ + n0 + wn + l15;
#pragma unroll
                for (int tj = 0; tj < 4; ++tj)
                    orow[tj * 16] = acc[ti][tj][r] + w1 * pbva[tj] + w2 * pbvb[tj];
            }
        }
    }
}

// ================= host launcher =================
extern "C" void kernel_launch(void* const* d_in, const int* in_sizes, int n_in,
                              void* d_out, int out_size, void* d_ws, size_t ws_size,
                              hipStream_t stream)
{
    const float* x   = (const float*)d_in[0];
    const float* gw1 = (const float*)d_in[1];
    const float* gb1 = (const float*)d_in[2];
    const float* gw2 = (const float*)d_in[3];
    const float* gb2 = (const float*)d_in[4];
    const float* pos = (const float*)d_in[5];
    const float* n1g = (const float*)d_in[6];
    const float* ipw = (const float*)d_in[7];
    const float* ipb = (const float*)d_in[8];
    const float* opw = (const float*)d_in[9];
    const float* opb = (const float*)d_in[10];
    const float* ls1 = (const float*)d_in[11];
    const float* n2g = (const float*)d_in[12];
    const float* fw1 = (const float*)d_in[13];
    const float* fb1 = (const float*)d_in[14];
    const float* fw2 = (const float*)d_in[15];
    const float* fb2 = (const float*)d_in[16];
    const float* ls2 = (const float*)d_in[17];
    const float* pw  = (const float*)d_in[18];
    const float* pb  = (const float*)d_in[19];

    float* out = (float*)d_out;

    char* ws = (char*)d_ws;
    int*   cnt      = (int*)(ws + 0);
    int*   pcnt     = (int*)(ws + 16);
    int*   offA     = (int*)(ws + 80);
    int*   poff     = (int*)(ws + 112);
    int*   topi     = (int*)(ws + WS_TOPI);
    float* topw     = (float*)(ws + WS_TOPW);
    int*   idx_list = (int*)(ws + WS_IDX);
    float* wgt_list = (float*)(ws + WS_WGT);
    int*   er0      = (int*)(ws + WS_ER0);
    int*   er1      = (int*)(ws + WS_ER1);
    int*   prk      = (int*)(ws + WS_PRK);
    int*   bbe      = (int*)(ws + WS_BBE);
    int*   bbp      = (int*)(ws + WS_BBP);
    int*   prA      = (int*)(ws + WS_PRA);
    int*   prB      = (int*)(ws + WS_PRB);
    float* pw1      = (float*)(ws + WS_PW1);
    float* pw2      = (float*)(ws + WS_PW2);
    int*   prow     = (int*)(ws + WS_PRW);
    __hip_bfloat16* xsf  = (__hip_bfloat16*)(ws + WS_XSF);
    __hip_bfloat16* pwb  = (__hip_bfloat16*)(ws + WS_PWB);
    __hip_bfloat16* ipwb = (__hip_bfloat16*)(ws + WS_IPWB);
    __hip_bfloat16* opwb = (__hip_bfloat16*)(ws + WS_OPWB);
    __hip_bfloat16* fw1b = (__hip_bfloat16*)(ws + WS_FW1B);
    __hip_bfloat16* fw2b = (__hip_bfloat16*)(ws + WS_FW2B);

    // zero counters + aux/load slots only (main out region is fully overwritten)
    hipMemsetAsync(d_ws, 0, 256, stream);
    hipMemsetAsync(out + (size_t)B_SZ * D_SZ, 0, 5 * sizeof(float), stream);

    float* load_out = out + (size_t)B_SZ * D_SZ + 1;

    convert_pw<<<NE * D_SZ * D_SZ / (256 * 8), 256, 0, stream>>>(pw, pwb);
    convert_small<<<(N_IPW + N_OPW + N_FW1 + N_FW2) / (256 * 8), 256, 0, stream>>>(
        ipw, opw, fw1, fw2, ipwb, opwb, fw1b, fw2b);
    gate_kernel<<<B_SZ, 64, 0, stream>>>(x, gw1, gb1, gw2, gb2, topi, topw);
    count_kernel<<<B_SZ / 256, 256, 0, stream>>>(topi, cnt, pcnt, er0, er1, prk, bbe, bbp);
    offsets_kernel<<<1, 64, 0, stream>>>(cnt, pcnt, offA, poff, load_out);
    fill_kernel<<<B_SZ / 256, 256, 0, stream>>>(topi, topw, offA, poff, er0, er1, prk,
                                                bbe, bbp, idx_list, wgt_list,
                                                prA, prB, pw1, pw2, prow);
    expert_inner<<<2 * B_SZ, 256, 0, stream>>>(x, pos, n1g, ipwb, ipb, opwb, opb, ls1,
                                               n2g, fw1b, fb1, fw2b, fb2, ls2,
                                               offA, idx_list, wgt_list, xsf);
    proj_pair<<<dim3(96, D_SZ / 128), 256, 0, stream>>>(
        xsf, pwb, pb, poff, prA, prB, pw1, pw2, prow, out);
}